// Round 9
// baseline (1830.878 us; speedup 1.0000x reference)
//
#include <hip/hip_runtime.h>

typedef __bf16 bf16x8 __attribute__((ext_vector_type(8)));
typedef float  f32x4  __attribute__((ext_vector_type(4)));

#define E_EDGES 100000
#define N_NODES 25000
#define N_GRAPHS 2048
#define HID 512
#define CAP 32

__device__ __forceinline__ void gload_lds16(const void* g, void* l) {
    __builtin_amdgcn_global_load_lds(
        (const __attribute__((address_space(1))) void*)g,
        (__attribute__((address_space(3))) void*)l, 16, 0, 0);
}

__device__ __forceinline__ __bf16 rtne(float x) {
    union { unsigned short s; __bf16 b; } u;
    unsigned v = __float_as_uint(x);
    u.s = (unsigned short)((v + 0x7FFF + ((v >> 16) & 1)) >> 16);
    return u.b;
}

__device__ __forceinline__ void split2(float x, __bf16& hi, __bf16& lo) {
    hi = rtne(x);
    lo = rtne(x - (float)hi);
}

__device__ __forceinline__ float ldf(const void* p, long i, int f32) {
    return f32 ? ((const float*)p)[i] : (float)(((const __bf16*)p)[i]);
}

// flags[0]=1 if float inputs are f32 (else bf16); flags[1]=1 if int inputs are i64
__global__ void probe_dtypes(const unsigned* __restrict__ xr, const unsigned* __restrict__ eir,
                             int* __restrict__ flags)
{
    __shared__ int cfp, ci;
    if (threadIdx.x == 0) { cfp = 0; ci = 0; }
    __syncthreads();
    int lc = 0;
    for (int i = threadIdx.x; i < 1024; i += 256) {
        unsigned elo = (xr[i] >> 7) & 0xFFu;
        if (elo > 140u) lc++;
    }
    atomicAdd(&cfp, lc);
    int ln = 0;
    for (int i = threadIdx.x; i < 512; i += 256) {
        if (eir[2 * i + 1] != 0u) ln++;
    }
    atomicAdd(&ci, ln);
    __syncthreads();
    if (threadIdx.x == 0) {
        flags[0] = (cfp > 100) ? 1 : 0;
        flags[1] = (ci < 256) ? 1 : 0;
    }
}

__global__ void to_int32(const void* __restrict__ src, int* __restrict__ dst, long n,
                         const int* __restrict__ flags)
{
    long i = (long)blockIdx.x * 256 + threadIdx.x;
    if (i >= n) return;
    dst[i] = flags[1] ? (int)((const long long*)src)[i] : ((const int*)src)[i];
}

// Tiled transpose+split: WThi/WTlo[n,k] = split(W[krow0 + z*512 + k, n]), zero-pad to Kpad.
__global__ __launch_bounds__(256) void split_transpose_t(
    const void* __restrict__ W, __bf16* __restrict__ Whi, __bf16* __restrict__ Wlo,
    int Ksrc, int N, int Kpad, int krow0, const int* __restrict__ flags)
{
    __shared__ float tile[64][65];
    const int z = blockIdx.z;
    const int nb = blockIdx.x * 64;
    const int kb = blockIdx.y * 64;
    const int f32m = flags[0];
    const int lx = threadIdx.x & 63;
    const size_t dsto = (size_t)z * N * Kpad;
    const int kro = krow0 + z * 512;

    for (int rr = threadIdx.x >> 6; rr < 64; rr += 4) {
        const int k = kb + rr;
        const int n = nb + lx;
        float v = 0.f;
        if (k < Ksrc && n < N) v = ldf(W, (size_t)(kro + k) * N + n, f32m);
        tile[rr][lx] = v;
    }
    __syncthreads();
    for (int rr = threadIdx.x >> 6; rr < 64; rr += 4) {
        const int n = nb + rr;
        const int k = kb + lx;
        if (n < N && k < Kpad) {
            __bf16 hi, lo; split2(tile[lx][rr], hi, lo);
            Whi[dsto + (size_t)n * Kpad + k] = hi;
            Wlo[dsto + (size_t)n * Kpad + k] = lo;
        }
    }
}

// A_init[e,0:160] = [x[row[e],0:133], ea[e,0:14], 0] -> hi/lo; one thread per 8-f chunk
__global__ void build_Ainit_split8(const void* __restrict__ x, const void* __restrict__ ea,
                                   const int* __restrict__ row, __bf16* __restrict__ Ah,
                                   __bf16* __restrict__ Al, const int* __restrict__ flags)
{
    long idx = (long)blockIdx.x * 256 + threadIdx.x;
    if (idx >= (long)E_EDGES * 20) return;
    const int e = (int)(idx / 20), c = (int)(idx % 20);
    const int f0 = c * 8;
    const int f32m = flags[0];
    const int r = row[e];
    bf16x8 oh, ol;
    #pragma unroll
    for (int j = 0; j < 8; ++j) {
        const int f = f0 + j;
        float v = 0.f;
        if (f < 133)      v = ldf(x, (size_t)r * 133 + f, f32m);
        else if (f < 147) v = ldf(ea, (size_t)e * 14 + (f - 133), f32m);
        __bf16 hi, lo; split2(v, hi, lo);
        oh[j] = hi; ol[j] = lo;
    }
    *(bf16x8*)(Ah + (size_t)e * 160 + f0) = oh;
    *(bf16x8*)(Al + (size_t)e * 160 + f0) = ol;
}

// A_e2n[n,0:672] = [x[n,0:133], s_f32[n,0:512], 0] -> hi/lo; one thread per 8-f chunk
__global__ void build_Ae2n_split8(const void* __restrict__ x, const float* __restrict__ s,
                                  __bf16* __restrict__ Ah, __bf16* __restrict__ Al,
                                  const int* __restrict__ flags)
{
    long idx = (long)blockIdx.x * 256 + threadIdx.x;
    if (idx >= (long)N_NODES * 84) return;
    const int n = (int)(idx / 84), c = (int)(idx % 84);
    const int f0 = c * 8;
    const int f32m = flags[0];
    bf16x8 oh, ol;
    #pragma unroll
    for (int j = 0; j < 8; ++j) {
        const int f = f0 + j;
        float v = 0.f;
        if (f < 133)      v = ldf(x, (size_t)n * 133 + f, f32m);
        else if (f < 645) v = s[(size_t)n * HID + (f - 133)];
        __bf16 hi, lo; split2(v, hi, lo);
        oh[j] = hi; ol[j] = lo;
    }
    *(bf16x8*)(Ah + (size_t)n * 672 + f0) = oh;
    *(bf16x8*)(Al + (size_t)n * 672 + f0) = ol;
}

// Wide split-precision GEMM: C[M,512] = relu(A @ BT^T + bias), 3-term MFMA.
__global__ __launch_bounds__(1024) void gemm3w(
    const __bf16* __restrict__ Ah, const __bf16* __restrict__ Al,
    const __bf16* __restrict__ Bh, const __bf16* __restrict__ Bl,
    const void* __restrict__ bias,
    void* __restrict__ C, int out_f32, int kmaj, int M, int K, const int* __restrict__ flags)
{
    __shared__ __bf16 lAh[128 * 32];
    __shared__ __bf16 lAl[128 * 32];
    __shared__ __bf16 lBh[512 * 32];

    const int m0 = blockIdx.x * 128;
    const int tid = threadIdx.x;
    const int w = tid >> 6;
    const int lane = tid & 63;

    const int ac = tid & 511;
    int arow = m0 + (ac >> 2); if (arow >= M) arow = M - 1;
    const int akc = (ac & 3) << 3;
    const __bf16* Asrc = (tid < 512) ? Ah : Al;
    const size_t ag = (size_t)arow * K + akc;
    __bf16* aw = ((tid < 512) ? lAh : lAl) + (ac >> 2) * 32 + akc;

    const size_t bg0 = (size_t)(tid >> 2) * K + ((tid & 3) << 3);
    const size_t bg1 = (size_t)((tid + 1024) >> 2) * K + (((tid + 1024) & 3) << 3);
    __bf16* wB0 = lBh + (size_t)tid * 8;
    __bf16* wB1 = lBh + (size_t)(tid + 1024) * 8;

    const int mh = (w >> 3) * 64;
    const int nq = (w & 7) * 64;
    const int c16 = lane & 15;
    const int quad = lane >> 4;

    const __bf16* blp = Bl + (size_t)(nq + c16) * K + quad * 8;

    f32x4 acc[4][4] = {};

    for (int k0 = 0; k0 < K; k0 += 32) {
        gload_lds16(Asrc + ag + k0, aw);
        gload_lds16(Bh + bg0 + k0, wB0);
        gload_lds16(Bh + bg1 + k0, wB1);
        __syncthreads();

        bf16x8 bl[4];
        #pragma unroll
        for (int j = 0; j < 4; ++j)
            bl[j] = *(const bf16x8*)(blp + (size_t)(j * 16) * K + k0);

        bf16x8 ah[4], al[4];
        #pragma unroll
        for (int i = 0; i < 4; ++i) {
            ah[i] = *(const bf16x8*)(lAh + (mh + i * 16 + c16) * 32 + quad * 8);
            al[i] = *(const bf16x8*)(lAl + (mh + i * 16 + c16) * 32 + quad * 8);
        }
        #pragma unroll
        for (int j = 0; j < 4; ++j) {
            bf16x8 bh = *(const bf16x8*)(lBh + (nq + j * 16 + c16) * 32 + quad * 8);
            #pragma unroll
            for (int i = 0; i < 4; ++i) {
                acc[i][j] = __builtin_amdgcn_mfma_f32_16x16x32_bf16(ah[i], bh, acc[i][j], 0, 0, 0);
                acc[i][j] = __builtin_amdgcn_mfma_f32_16x16x32_bf16(al[i], bh, acc[i][j], 0, 0, 0);
                acc[i][j] = __builtin_amdgcn_mfma_f32_16x16x32_bf16(ah[i], bl[j], acc[i][j], 0, 0, 0);
            }
        }
        __syncthreads();
    }

    const int f32 = flags[0];
    const size_t kstride = (size_t)M * 32;
    #pragma unroll
    for (int j = 0; j < 4; ++j) {
        const int gcol = nq + j * 16 + c16;
        const float bv = ldf(bias, gcol, f32);
        #pragma unroll
        for (int i = 0; i < 4; ++i) {
            const int growb = m0 + mh + i * 16 + quad * 4;
            #pragma unroll
            for (int rr = 0; rr < 4; ++rr) {
                const int grow = growb + rr;
                if (grow < M) {
                    float v = acc[i][j][rr] + bv;
                    v = v > 0.f ? v : 0.f;
                    if (out_f32)   ((float*)C)[(size_t)grow * HID + gcol] = v;
                    else if (kmaj) ((__bf16*)C)[(size_t)(gcol >> 5) * kstride + (size_t)grow * 32 + (gcol & 31)] = rtne(v);
                    else           ((__bf16*)C)[(size_t)grow * HID + gcol] = rtne(v);
                }
            }
        }
    }
}

// Streaming GEMM g = h @ W^T, 512-thr / BM=128 / BN=256 col-split: 2 blocks/CU.
// REQUIRES src != dst. Used for layer 0 (h0 -> h). [r6-identical: control kernel]
__global__ __launch_bounds__(512, 4) void gemmg512(
    const __bf16* __restrict__ hsrc, const __bf16* __restrict__ Bh,
    const __bf16* __restrict__ Bl, __bf16* __restrict__ g, int M)
{
    __shared__ __bf16 lA[128 * 32];   //  8KB
    __shared__ __bf16 lB[256 * 32];   // 16KB

    const int m0 = blockIdx.x * 128;
    const int nc = blockIdx.y * 256;
    const int tid = threadIdx.x;
    const int w = tid >> 6;
    const int lane = tid & 63;
    const size_t kstride = (size_t)M * 32;

    const int c0 = tid, c1 = tid + 512;
    const size_t bg0 = (size_t)(nc + (c0 >> 2)) * HID + ((c0 & 3) << 3);
    const size_t bg1 = (size_t)(nc + (c1 >> 2)) * HID + ((c1 & 3) << 3);

    const int mh = (w >> 2) * 64;
    const int nqw = (w & 3) * 64;
    const int c16 = lane & 15;
    const int quad = lane >> 4;
    const __bf16* blp = Bl + (size_t)(nc + nqw + c16) * HID + quad * 8;

    f32x4 acc[4][4] = {};

    for (int t = 0; t < 16; ++t) {
        const int k0 = t << 5;
        gload_lds16(hsrc + (size_t)t * kstride + (size_t)m0 * 32 + tid * 8, &lA[tid * 8]);
        gload_lds16(Bh + bg0 + k0, &lB[c0 * 8]);
        gload_lds16(Bh + bg1 + k0, &lB[c1 * 8]);
        __syncthreads();

        bf16x8 bl4[4];
        #pragma unroll
        for (int j = 0; j < 4; ++j)
            bl4[j] = *(const bf16x8*)(blp + (size_t)(j * 16) * HID + k0);

        bf16x8 ah[4];
        #pragma unroll
        for (int i = 0; i < 4; ++i)
            ah[i] = *(const bf16x8*)&lA[(mh + i * 16 + c16) * 32 + quad * 8];

        #pragma unroll
        for (int j = 0; j < 4; ++j) {
            bf16x8 bh = *(const bf16x8*)&lB[(nqw + j * 16 + c16) * 32 + quad * 8];
            #pragma unroll
            for (int i = 0; i < 4; ++i) {
                acc[i][j] = __builtin_amdgcn_mfma_f32_16x16x32_bf16(ah[i], bh, acc[i][j], 0, 0, 0);
                acc[i][j] = __builtin_amdgcn_mfma_f32_16x16x32_bf16(ah[i], bl4[j], acc[i][j], 0, 0, 0);
            }
        }
        __syncthreads();
    }

    #pragma unroll
    for (int j = 0; j < 4; ++j) {
        const int gcol = nc + nqw + j * 16 + c16;
        const size_t cb = (size_t)(gcol >> 5) * kstride + (gcol & 31);
        #pragma unroll
        for (int i = 0; i < 4; ++i) {
            const int growb = m0 + mh + i * 16 + quad * 4;
            #pragma unroll
            for (int rr = 0; rr < 4; ++rr) {
                const int grow = growb + rr;
                if (grow < M)
                    g[cb + (size_t)grow * 32] = rtne(acc[i][j][rr]);
            }
        }
    }
}

// In-place-safe conv GEMM, r9: BK=64 (halves barrier count: 8 iters x 2
// barriers vs 16 x 2) + source-side XOR chunk-swizzle on BOTH LDS tiles
// (rule #21: gload_lds dst must be linear, so the GLOBAL source address is
// permuted and reads apply the matching XOR). Bank math: ah and bh reads
// land 2 lanes/bank-quad (free, m136) vs 8-way before. Numerics identical
// to r6 (same MFMA sequence; Bl still read from global per-wave).
// 1024 thr / BM=128 / BN=512: block owns all cols of its rows -> in-place OK.
__global__ __launch_bounds__(1024) void gemmg1024(
    const __bf16* __restrict__ hsrc, const __bf16* __restrict__ Bh,
    const __bf16* __restrict__ Bl, __bf16* __restrict__ g, int M)
{
    __shared__ __bf16 lA[2 * 128 * 32];   // 16KB: [panel][row][4 chunks of 8, swz]
    __shared__ __bf16 lB[512 * 64];       // 64KB: [col][8 chunks of 8, swz]

    const int m0 = blockIdx.x * 128;
    const int tid = threadIdx.x;
    const int w = tid >> 6;
    const int lane = tid & 63;
    const size_t kstride = (size_t)M * 32;

    // A staging: thread -> (panel=tid>>9, chunk ac); src chunk swizzled by row
    const int apan = tid >> 9;
    const int ac = tid & 511;
    const int arow = ac >> 2;
    const int acs = (ac & 3) ^ ((arow >> 1) & 3);          // swizzled src chunk
    const size_t asrc0 = (size_t)m0 * 32 + (size_t)arow * 32 + (size_t)acs * 8;
    const int adst = apan * 4096 + ac * 8;

    const int mh = (w >> 3) * 64;
    const int nq = (w & 7) * 64;
    const int c16 = lane & 15;
    const int quad = lane >> 4;
    const __bf16* blp = Bl + (size_t)(nq + c16) * HID + quad * 8;

    // read-side swizzle constants
    const int aswz = (quad ^ ((c16 >> 1) & 3)) << 3;       // A chunk offset (elems)
    const int bx = c16 & 7;                                 // B col&7

    f32x4 acc[4][4] = {};

    for (int t = 0; t < 8; ++t) {
        const int k0 = t << 6;
        // A: two k-slabs (2t, 2t+1) -> panels 0/1
        gload_lds16(hsrc + (size_t)(2 * t + apan) * kstride + asrc0, lA + adst);
        // B: 4 chunk-ids/thread; lds chunk (ci&7) of col holds global chunk (ci&7)^(col&7)
        #pragma unroll
        for (int q = 0; q < 4; ++q) {
            const int ci = tid + q * 1024;
            const int col = ci >> 3;
            const int cc = (ci & 7) ^ (col & 7);
            gload_lds16(Bh + (size_t)col * HID + k0 + (cc << 3), lB + col * 64 + ((ci & 7) << 3));
        }
        __syncthreads();

        #pragma unroll
        for (int p = 0; p < 2; ++p) {
            bf16x8 bl4[4];
            #pragma unroll
            for (int j = 0; j < 4; ++j)
                bl4[j] = *(const bf16x8*)(blp + (size_t)(j * 16) * HID + k0 + p * 32);

            bf16x8 ah[4];
            #pragma unroll
            for (int i = 0; i < 4; ++i)
                ah[i] = *(const bf16x8*)&lA[p * 4096 + (mh + i * 16 + c16) * 32 + aswz];

            const int bq = ((p * 4 + quad) ^ bx) << 3;     // B chunk offset (elems)
            #pragma unroll
            for (int j = 0; j < 4; ++j) {
                bf16x8 bh = *(const bf16x8*)&lB[(nq + j * 16 + c16) * 64 + bq];
                #pragma unroll
                for (int i = 0; i < 4; ++i) {
                    acc[i][j] = __builtin_amdgcn_mfma_f32_16x16x32_bf16(ah[i], bh, acc[i][j], 0, 0, 0);
                    acc[i][j] = __builtin_amdgcn_mfma_f32_16x16x32_bf16(ah[i], bl4[j], acc[i][j], 0, 0, 0);
                }
            }
        }
        __syncthreads();
    }

    #pragma unroll
    for (int j = 0; j < 4; ++j) {
        const int gcol = nq + j * 16 + c16;
        const size_t cb = (size_t)(gcol >> 5) * kstride + (gcol & 31);
        #pragma unroll
        for (int i = 0; i < 4; ++i) {
            const int growb = m0 + mh + i * 16 + quad * 4;
            #pragma unroll
            for (int rr = 0; rr < 4; ++rr) {
                const int grow = growb + rr;
                if (grow < M)
                    g[cb + (size_t)grow * 32] = rtne(acc[i][j][rr]);
            }
        }
    }
}

// h[e] = relu(gs[row[e]] - g[e^1] + b + h0[e]); one thread per (edge-pair, 8-col
// chunk); a wave = one pair (64 chunks) so gs row reads coalesce.
__global__ __launch_bounds__(256) void combine_msg(
    const __bf16* __restrict__ g, const __bf16* __restrict__ gs,
    const int* __restrict__ row, const void* __restrict__ bias, int bias_off,
    const __bf16* __restrict__ h0, __bf16* __restrict__ hdst,
    const int* __restrict__ flags)
{
    long idx = (long)blockIdx.x * 256 + threadIdx.x;
    if (idx >= (long)(E_EDGES / 2) * 64) return;
    const int p = (int)(idx >> 6);
    const int c = (int)(idx & 63);
    const int kb = c >> 2;
    const int off = (c & 3) << 3;
    const int e0 = 2 * p, e1 = 2 * p + 1;
    const int u0 = row[e0], u1 = row[e1];
    const size_t kstride = (size_t)E_EDGES * 32;
    const size_t gb = (size_t)kb * kstride + off;
    const int k = kb * 32 + off;

    bf16x8 g0 = *(const bf16x8*)(g + gb + (size_t)e0 * 32);
    bf16x8 g1 = *(const bf16x8*)(g + gb + (size_t)e1 * 32);
    bf16x8 r0 = *(const bf16x8*)(h0 + gb + (size_t)e0 * 32);
    bf16x8 r1 = *(const bf16x8*)(h0 + gb + (size_t)e1 * 32);
    bf16x8 s0 = *(const bf16x8*)(gs + (size_t)u0 * HID + k);
    bf16x8 s1 = *(const bf16x8*)(gs + (size_t)u1 * HID + k);

    const int f32 = flags[0];
    bf16x8 o0, o1;
    #pragma unroll
    for (int j = 0; j < 8; ++j) {
        const float bv = ldf(bias, bias_off + k + j, f32);
        float v0 = (float)s0[j] - (float)g1[j] + bv + (float)r0[j];
        float v1 = (float)s1[j] - (float)g0[j] + bv + (float)r1[j];
        o0[j] = rtne(v0 > 0.f ? v0 : 0.f);
        o1[j] = rtne(v1 > 0.f ? v1 : 0.f);
    }
    *(bf16x8*)(hdst + gb + (size_t)e0 * 32) = o0;
    *(bf16x8*)(hdst + gb + (size_t)e1 * 32) = o1;
}

__global__ void bucket_build(const int* __restrict__ col, int* __restrict__ counts,
                             int* __restrict__ buckets, int E)
{
    int e = blockIdx.x * 256 + threadIdx.x;
    if (e >= E) return;
    int c = col[e];
    int p = atomicAdd(&counts[c], 1);
    if (p < CAP) buckets[(size_t)c * CAP + p] = e;
}

// Vectorized segsum: one thread per (node, 8-feature chunk); input K-MAJOR [16][E][32].
__global__ __launch_bounds__(256) void segsum8(
    const __bf16* __restrict__ h, const int* __restrict__ counts,
    const int* __restrict__ buckets, __bf16* __restrict__ abf,
    float* __restrict__ af32)
{
    const int nid = blockIdx.x * 4 + (threadIdx.x >> 6);
    const int fc = threadIdx.x & 63;
    if (nid >= N_NODES) return;
    const int kb = fc >> 2;
    const int off = (fc & 3) << 3;
    const size_t base = (size_t)kb * ((size_t)E_EDGES * 32) + off;
    int cnt = counts[nid]; if (cnt > CAP) cnt = CAP;
    const int* bl = buckets + (size_t)nid * CAP;
    float s[8] = {0.f, 0.f, 0.f, 0.f, 0.f, 0.f, 0.f, 0.f};
    for (int i = 0; i < cnt; ++i) {
        const int e = bl[i];
        bf16x8 v = *(const bf16x8*)(h + base + (size_t)e * 32);
        #pragma unroll
        for (int j = 0; j < 8; ++j) s[j] += (float)v[j];
    }
    if (af32) {
        f32x4* out = (f32x4*)(af32 + (size_t)nid * HID + fc * 8);
        out[0] = f32x4{s[0], s[1], s[2], s[3]};
        out[1] = f32x4{s[4], s[5], s[6], s[7]};
    } else {
        bf16x8 o;
        #pragma unroll
        for (int j = 0; j < 8; ++j) o[j] = rtne(s[j]);
        *(bf16x8*)(abf + (size_t)nid * HID + fc * 8) = o;
    }
}

__global__ void graph_starts(const int* __restrict__ batch, int* __restrict__ gstart, int N, int G)
{
    int n = blockIdx.x * 256 + threadIdx.x;
    if (n >= N) return;
    int b = batch[n];
    if (n == 0) {
        for (int g = 0; g <= b; ++g) gstart[g] = 0;
    } else {
        int pb = batch[n - 1];
        for (int g = pb + 1; g <= b; ++g) gstart[g] = n;
    }
    if (n == N - 1) {
        for (int g = b + 1; g <= G; ++g) gstart[g] = N;
    }
}

__global__ void pool_nodes(const float* __restrict__ hn, const int* __restrict__ gstart,
                           float* __restrict__ Apool)
{
    int g = blockIdx.x;
    int s = gstart[g], e = gstart[g + 1];
    for (int f = threadIdx.x; f < HID; f += 256) {
        float acc = 0.f;
        for (int n = s; n < e; ++n) acc += hn[(size_t)n * HID + f];
        Apool[(size_t)g * HID + f] = acc;
    }
}

// fused ffn: per block 8 graphs; t = relu(Apool@W1+b1); out = t@W2 + b2 (all f32)
__global__ __launch_bounds__(256) void ffn_fused(
    const float* __restrict__ Apool, const void* __restrict__ W1,
    const void* __restrict__ b1, const void* __restrict__ W2,
    const void* __restrict__ b2v, void* __restrict__ outv,
    const int* __restrict__ flags)
{
    __shared__ float sA[8][512];
    __shared__ float t[8][512];
    __shared__ float sW2[512];
    __shared__ float red[4];
    const int tid = threadIdx.x;
    const int g0 = blockIdx.x * 8;
    const int f32 = flags[0];

    for (int i = tid; i < 4096; i += 256)
        sA[i >> 9][i & 511] = Apool[(size_t)g0 * 512 + i];
    for (int n = tid; n < 512; n += 256)
        sW2[n] = ldf(W2, n, f32);
    __syncthreads();

    {
        float acc0[8], acc1[8];
        const float bb0 = ldf(b1, tid, f32);
        const float bb1 = ldf(b1, tid + 256, f32);
        #pragma unroll
        for (int gi = 0; gi < 8; ++gi) { acc0[gi] = bb0; acc1[gi] = bb1; }
        if (f32) {
            const float* Wf = (const float*)W1;
            for (int k = 0; k < 512; ++k) {
                float w0 = Wf[(size_t)k * 512 + tid];
                float w1 = Wf[(size_t)k * 512 + tid + 256];
                #pragma unroll
                for (int gi = 0; gi < 8; ++gi) {
                    float a = sA[gi][k];
                    acc0[gi] += a * w0;
                    acc1[gi] += a * w1;
                }
            }
        } else {
            const __bf16* Wb = (const __bf16*)W1;
            for (int k = 0; k < 512; ++k) {
                float w0 = (float)Wb[(size_t)k * 512 + tid];
                float w1 = (float)Wb[(size_t)k * 512 + tid + 256];
                #pragma unroll
                for (int gi = 0; gi < 8; ++gi) {
                    float a = sA[gi][k];
                    acc0[gi] += a * w0;
                    acc1[gi] += a * w1;
                }
            }
        }
        #pragma unroll
        for (int gi = 0; gi < 8; ++gi) {
            t[gi][tid]       = acc0[gi] > 0.f ? acc0[gi] : 0.f;
            t[gi][tid + 256] = acc1[gi] > 0.f ? acc1[gi] : 0.f;
        }
    }
    __syncthreads();

    const int lane = tid & 63;
    const int w = tid >> 6;
    const float b2 = ldf(b2v, 0, f32);
    for (int gi = 0; gi < 8; ++gi) {
        float p = t[gi][tid] * sW2[tid] + t[gi][tid + 256] * sW2[tid + 256];
        for (int o = 32; o; o >>= 1) p += __shfl_down(p, o, 64);
        if (lane == 0) red[w] = p;
        __syncthreads();
        if (tid == 0) {
            float r = red[0] + red[1] + red[2] + red[3] + b2;
            if (f32) ((float*)outv)[g0 + gi] = r;
            else     ((__bf16*)outv)[g0 + gi] = rtne(r);
        }
        __syncthreads();
    }
}

extern "C" void kernel_launch(void* const* d_in, const int* in_sizes, int n_in,
                              void* d_out, int out_size, void* d_ws, size_t ws_size,
                              hipStream_t stream)
{
    const int E = E_EDGES, NN = N_NODES, G = N_GRAPHS;

    char* wsp = (char*)d_ws;
    size_t off = 0;
    auto carve = [&](size_t bytes) -> void* {
        void* p = wsp + off;
        off += (bytes + 511) & ~(size_t)511;
        return p;
    };

    // r6 carve order restored exactly (r8's end-of-ws state placement regressed
    // gemmg1024 198->225 via cache-placement effects).
    __bf16* h0    = (__bf16*)carve((size_t)E * HID * 2);   // k-major [16][E][32]
    __bf16* h     = (__bf16*)carve((size_t)E * HID * 2);   // k-major; layer state
    __bf16* abuf  = (__bf16*)carve((size_t)NN * HID * 2);  // row-major; gs each layer
    float*  Apool = (float*) carve((size_t)G * HID * 4);
    __bf16* WTih  = (__bf16*)carve((size_t)512 * 160 * 2);
    __bf16* WTil  = (__bf16*)carve((size_t)512 * 160 * 2);
    __bf16* WTch  = (__bf16*)carve((size_t)4 * 512 * 512 * 2);
    __bf16* WTcl  = (__bf16*)carve((size_t)4 * 512 * 512 * 2);
    __bf16* WTqh  = (__bf16*)carve((size_t)512 * 672 * 2);
    __bf16* WTql  = (__bf16*)carve((size_t)512 * 672 * 2);
    int*    ei32  = (int*)   carve((size_t)2 * E * 4);
    int*    b32   = (int*)   carve((size_t)NN * 4);
    int*    counts= (int*)   carve((size_t)NN * 4);
    int*    bucket= (int*)   carve((size_t)NN * CAP * 4);
    int*    gstart= (int*)   carve((size_t)(G + 1) * 4);
    int*    flags = (int*)   carve(2 * 4);

    // aliases into provably-dead regions
    __bf16* Aih = h;                              // E*160 bf16; h dead until layer-0 output
    __bf16* Ail = h + (size_t)E * 160;
    __bf16* Aqh = h;                              // h dead after final segsum
    __bf16* Aql = h + (size_t)NN * 672;
    float*  hn   = (float*)h0;                    // NN*512 f32; h0 dead after layer-3 combine
    float*  sfin = (float*)((char*)h0 + (size_t)NN * HID * 4);  // NN*512 f32 (row-major)

    if (off > ws_size) {  // clean fail instead of faulting
        hipMemsetAsync(d_out, 0, (size_t)out_size * 4, stream);
        return;
    }

    auto cdiv = [](long a, long b) { return (int)((a + b - 1) / b); };

    probe_dtypes<<<1, 256, 0, stream>>>((const unsigned*)d_in[0], (const unsigned*)d_in[1], flags);
    to_int32<<<cdiv((long)2 * E, 256), 256, 0, stream>>>(d_in[1], ei32, (long)2 * E, flags);
    to_int32<<<cdiv(NN, 256), 256, 0, stream>>>(d_in[3], b32, NN, flags);

    const int* row = ei32;
    const int* col = ei32 + E;

    hipMemsetAsync(counts, 0, (size_t)NN * 4, stream);

    split_transpose_t<<<dim3(8, 3, 1), 256, 0, stream>>>(d_in[4], WTih, WTil, 147, 512, 160, 0, flags);
    split_transpose_t<<<dim3(8, 8, 4), 256, 0, stream>>>(d_in[6], WTch, WTcl, 512, 512, 512, 0, flags);
    split_transpose_t<<<dim3(8, 11, 1), 256, 0, stream>>>(d_in[8], WTqh, WTql, 645, 512, 672, 0, flags);

    bucket_build<<<cdiv(E, 256), 256, 0, stream>>>(col, counts, bucket, E);

    // edge init: h0 = relu([x[row], ea] @ W_ei + b_ei) -> k-major  (wide 3-term GEMM)
    build_Ainit_split8<<<cdiv((long)E * 20, 256), 256, 0, stream>>>(d_in[0], d_in[2], row, Aih, Ail, flags);
    gemm3w<<<cdiv(E, 128), 1024, 0, stream>>>(Aih, Ail, WTih, WTil, d_in[5], h0, 0, 1, E, 160, flags);

    // DMPNN layers: g = h@W; gs = segsum(g); h = relu(gs[row] - g[rev] + b + h0)
    const long ncomb = (long)(E / 2) * 64;
    for (int l = 0; l < 4; ++l) {
        const __bf16* Wh = WTch + (size_t)l * 512 * 512;
        const __bf16* Wl = WTcl + (size_t)l * 512 * 512;
        if (l == 0)   // h0 -> h: src != dst, col-split 2-blocks/CU
            gemmg512<<<dim3(cdiv(E, 128), 2), 512, 0, stream>>>(h0, Wh, Wl, h, E);
        else          // h -> h in-place: BK=64 + swizzle variant
            gemmg1024<<<cdiv(E, 128), 1024, 0, stream>>>(h, Wh, Wl, h, E);
        segsum8<<<cdiv(NN, 4), 256, 0, stream>>>(h, counts, bucket, abuf, nullptr);
        combine_msg<<<cdiv(ncomb, 256), 256, 0, stream>>>(h, abuf, row, d_in[7], l * 512, h0, h, flags);
    }

    // final aggregation (f32, row-major out) + e2n (wide 3-term GEMM, f32 row-major out)
    segsum8<<<cdiv(NN, 4), 256, 0, stream>>>(h, counts, bucket, nullptr, sfin);
    build_Ae2n_split8<<<cdiv((long)NN * 84, 256), 256, 0, stream>>>(d_in[0], sfin, Aqh, Aql, flags);
    gemm3w<<<cdiv(NN, 128), 1024, 0, stream>>>(Aqh, Aql, WTqh, WTql, d_in[9], hn, 1, 0, NN, 672, flags);

    // pool + fused ffn (all f32)
    graph_starts<<<cdiv(NN, 256), 256, 0, stream>>>(b32, gstart, NN, G);
    pool_nodes<<<G, 256, 0, stream>>>(hn, gstart, Apool);
    ffn_fused<<<G / 8, 256, 0, stream>>>(Apool, d_in[10], d_in[11], d_in[12], d_in[13], d_out, flags);
}

// Round 10
// 1613.651 us; speedup vs baseline: 1.1346x; 1.1346x over previous
//
#include <hip/hip_runtime.h>

typedef __bf16 bf16x8 __attribute__((ext_vector_type(8)));
typedef float  f32x4  __attribute__((ext_vector_type(4)));

#define E_EDGES 100000
#define N_NODES 25000
#define N_GRAPHS 2048
#define HID 512
#define CAP 32

__device__ __forceinline__ void gload_lds16(const void* g, void* l) {
    __builtin_amdgcn_global_load_lds(
        (const __attribute__((address_space(1))) void*)g,
        (__attribute__((address_space(3))) void*)l, 16, 0, 0);
}

__device__ __forceinline__ __bf16 rtne(float x) {
    union { unsigned short s; __bf16 b; } u;
    unsigned v = __float_as_uint(x);
    u.s = (unsigned short)((v + 0x7FFF + ((v >> 16) & 1)) >> 16);
    return u.b;
}

__device__ __forceinline__ void split2(float x, __bf16& hi, __bf16& lo) {
    hi = rtne(x);
    lo = rtne(x - (float)hi);
}

__device__ __forceinline__ float ldf(const void* p, long i, int f32) {
    return f32 ? ((const float*)p)[i] : (float)(((const __bf16*)p)[i]);
}

// flags[0]=1 if float inputs are f32 (else bf16); flags[1]=1 if int inputs are i64
__global__ void probe_dtypes(const unsigned* __restrict__ xr, const unsigned* __restrict__ eir,
                             int* __restrict__ flags)
{
    __shared__ int cfp, ci;
    if (threadIdx.x == 0) { cfp = 0; ci = 0; }
    __syncthreads();
    int lc = 0;
    for (int i = threadIdx.x; i < 1024; i += 256) {
        unsigned elo = (xr[i] >> 7) & 0xFFu;
        if (elo > 140u) lc++;
    }
    atomicAdd(&cfp, lc);
    int ln = 0;
    for (int i = threadIdx.x; i < 512; i += 256) {
        if (eir[2 * i + 1] != 0u) ln++;
    }
    atomicAdd(&ci, ln);
    __syncthreads();
    if (threadIdx.x == 0) {
        flags[0] = (cfp > 100) ? 1 : 0;
        flags[1] = (ci < 256) ? 1 : 0;
    }
}

__global__ void to_int32(const void* __restrict__ src, int* __restrict__ dst, long n,
                         const int* __restrict__ flags)
{
    long i = (long)blockIdx.x * 256 + threadIdx.x;
    if (i >= n) return;
    dst[i] = flags[1] ? (int)((const long long*)src)[i] : ((const int*)src)[i];
}

// Tiled transpose+split: WThi/WTlo[n,k] = split(W[krow0 + z*512 + k, n]), zero-pad to Kpad.
__global__ __launch_bounds__(256) void split_transpose_t(
    const void* __restrict__ W, __bf16* __restrict__ Whi, __bf16* __restrict__ Wlo,
    int Ksrc, int N, int Kpad, int krow0, const int* __restrict__ flags)
{
    __shared__ float tile[64][65];
    const int z = blockIdx.z;
    const int nb = blockIdx.x * 64;
    const int kb = blockIdx.y * 64;
    const int f32m = flags[0];
    const int lx = threadIdx.x & 63;
    const size_t dsto = (size_t)z * N * Kpad;
    const int kro = krow0 + z * 512;

    for (int rr = threadIdx.x >> 6; rr < 64; rr += 4) {
        const int k = kb + rr;
        const int n = nb + lx;
        float v = 0.f;
        if (k < Ksrc && n < N) v = ldf(W, (size_t)(kro + k) * N + n, f32m);
        tile[rr][lx] = v;
    }
    __syncthreads();
    for (int rr = threadIdx.x >> 6; rr < 64; rr += 4) {
        const int n = nb + rr;
        const int k = kb + lx;
        if (n < N && k < Kpad) {
            __bf16 hi, lo; split2(tile[lx][rr], hi, lo);
            Whi[dsto + (size_t)n * Kpad + k] = hi;
            Wlo[dsto + (size_t)n * Kpad + k] = lo;
        }
    }
}

// A_init[e,0:160] = [x[row[e],0:133], ea[e,0:14], 0] -> hi/lo; one thread per 8-f chunk
__global__ void build_Ainit_split8(const void* __restrict__ x, const void* __restrict__ ea,
                                   const int* __restrict__ row, __bf16* __restrict__ Ah,
                                   __bf16* __restrict__ Al, const int* __restrict__ flags)
{
    long idx = (long)blockIdx.x * 256 + threadIdx.x;
    if (idx >= (long)E_EDGES * 20) return;
    const int e = (int)(idx / 20), c = (int)(idx % 20);
    const int f0 = c * 8;
    const int f32m = flags[0];
    const int r = row[e];
    bf16x8 oh, ol;
    #pragma unroll
    for (int j = 0; j < 8; ++j) {
        const int f = f0 + j;
        float v = 0.f;
        if (f < 133)      v = ldf(x, (size_t)r * 133 + f, f32m);
        else if (f < 147) v = ldf(ea, (size_t)e * 14 + (f - 133), f32m);
        __bf16 hi, lo; split2(v, hi, lo);
        oh[j] = hi; ol[j] = lo;
    }
    *(bf16x8*)(Ah + (size_t)e * 160 + f0) = oh;
    *(bf16x8*)(Al + (size_t)e * 160 + f0) = ol;
}

// A_e2n[n,0:672] = [x[n,0:133], s_f32[n,0:512], 0] -> hi/lo; one thread per 8-f chunk
__global__ void build_Ae2n_split8(const void* __restrict__ x, const float* __restrict__ s,
                                  __bf16* __restrict__ Ah, __bf16* __restrict__ Al,
                                  const int* __restrict__ flags)
{
    long idx = (long)blockIdx.x * 256 + threadIdx.x;
    if (idx >= (long)N_NODES * 84) return;
    const int n = (int)(idx / 84), c = (int)(idx % 84);
    const int f0 = c * 8;
    const int f32m = flags[0];
    bf16x8 oh, ol;
    #pragma unroll
    for (int j = 0; j < 8; ++j) {
        const int f = f0 + j;
        float v = 0.f;
        if (f < 133)      v = ldf(x, (size_t)n * 133 + f, f32m);
        else if (f < 645) v = s[(size_t)n * HID + (f - 133)];
        __bf16 hi, lo; split2(v, hi, lo);
        oh[j] = hi; ol[j] = lo;
    }
    *(bf16x8*)(Ah + (size_t)n * 672 + f0) = oh;
    *(bf16x8*)(Al + (size_t)n * 672 + f0) = ol;
}

// Wide split-precision GEMM: C[M,512] = relu(A @ BT^T + bias), 3-term MFMA.
__global__ __launch_bounds__(1024) void gemm3w(
    const __bf16* __restrict__ Ah, const __bf16* __restrict__ Al,
    const __bf16* __restrict__ Bh, const __bf16* __restrict__ Bl,
    const void* __restrict__ bias,
    void* __restrict__ C, int out_f32, int kmaj, int M, int K, const int* __restrict__ flags)
{
    __shared__ __bf16 lAh[128 * 32];
    __shared__ __bf16 lAl[128 * 32];
    __shared__ __bf16 lBh[512 * 32];

    const int m0 = blockIdx.x * 128;
    const int tid = threadIdx.x;
    const int w = tid >> 6;
    const int lane = tid & 63;

    const int ac = tid & 511;
    int arow = m0 + (ac >> 2); if (arow >= M) arow = M - 1;
    const int akc = (ac & 3) << 3;
    const __bf16* Asrc = (tid < 512) ? Ah : Al;
    const size_t ag = (size_t)arow * K + akc;
    __bf16* aw = ((tid < 512) ? lAh : lAl) + (ac >> 2) * 32 + akc;

    const size_t bg0 = (size_t)(tid >> 2) * K + ((tid & 3) << 3);
    const size_t bg1 = (size_t)((tid + 1024) >> 2) * K + (((tid + 1024) & 3) << 3);
    __bf16* wB0 = lBh + (size_t)tid * 8;
    __bf16* wB1 = lBh + (size_t)(tid + 1024) * 8;

    const int mh = (w >> 3) * 64;
    const int nq = (w & 7) * 64;
    const int c16 = lane & 15;
    const int quad = lane >> 4;

    const __bf16* blp = Bl + (size_t)(nq + c16) * K + quad * 8;

    f32x4 acc[4][4] = {};

    for (int k0 = 0; k0 < K; k0 += 32) {
        gload_lds16(Asrc + ag + k0, aw);
        gload_lds16(Bh + bg0 + k0, wB0);
        gload_lds16(Bh + bg1 + k0, wB1);
        __syncthreads();

        bf16x8 bl[4];
        #pragma unroll
        for (int j = 0; j < 4; ++j)
            bl[j] = *(const bf16x8*)(blp + (size_t)(j * 16) * K + k0);

        bf16x8 ah[4], al[4];
        #pragma unroll
        for (int i = 0; i < 4; ++i) {
            ah[i] = *(const bf16x8*)(lAh + (mh + i * 16 + c16) * 32 + quad * 8);
            al[i] = *(const bf16x8*)(lAl + (mh + i * 16 + c16) * 32 + quad * 8);
        }
        #pragma unroll
        for (int j = 0; j < 4; ++j) {
            bf16x8 bh = *(const bf16x8*)(lBh + (nq + j * 16 + c16) * 32 + quad * 8);
            #pragma unroll
            for (int i = 0; i < 4; ++i) {
                acc[i][j] = __builtin_amdgcn_mfma_f32_16x16x32_bf16(ah[i], bh, acc[i][j], 0, 0, 0);
                acc[i][j] = __builtin_amdgcn_mfma_f32_16x16x32_bf16(al[i], bh, acc[i][j], 0, 0, 0);
                acc[i][j] = __builtin_amdgcn_mfma_f32_16x16x32_bf16(ah[i], bl[j], acc[i][j], 0, 0, 0);
            }
        }
        __syncthreads();
    }

    const int f32 = flags[0];
    const size_t kstride = (size_t)M * 32;
    #pragma unroll
    for (int j = 0; j < 4; ++j) {
        const int gcol = nq + j * 16 + c16;
        const float bv = ldf(bias, gcol, f32);
        #pragma unroll
        for (int i = 0; i < 4; ++i) {
            const int growb = m0 + mh + i * 16 + quad * 4;
            #pragma unroll
            for (int rr = 0; rr < 4; ++rr) {
                const int grow = growb + rr;
                if (grow < M) {
                    float v = acc[i][j][rr] + bv;
                    v = v > 0.f ? v : 0.f;
                    if (out_f32)   ((float*)C)[(size_t)grow * HID + gcol] = v;
                    else if (kmaj) ((__bf16*)C)[(size_t)(gcol >> 5) * kstride + (size_t)grow * 32 + (gcol & 31)] = rtne(v);
                    else           ((__bf16*)C)[(size_t)grow * HID + gcol] = rtne(v);
                }
            }
        }
    }
}

// Streaming GEMM g = h @ W^T, ROW-MAJOR [E][512] state (r10). 512-thr /
// BM=128 / BN=256 col-split: 2 blocks/CU. REQUIRES src != dst (layer 0).
// A staging = gemm3w's proven row-major pattern; LDS tile layout unchanged.
__global__ __launch_bounds__(512, 4) void gemmg512(
    const __bf16* __restrict__ hsrc, const __bf16* __restrict__ Bh,
    const __bf16* __restrict__ Bl, __bf16* __restrict__ g, int M)
{
    __shared__ __bf16 lA[128 * 32];   //  8KB
    __shared__ __bf16 lB[256 * 32];   // 16KB

    const int m0 = blockIdx.x * 128;
    const int nc = blockIdx.y * 256;
    const int tid = threadIdx.x;
    const int w = tid >> 6;
    const int lane = tid & 63;

    int arow = m0 + (tid >> 2); if (arow >= M) arow = M - 1;
    const size_t ag = (size_t)arow * HID + ((tid & 3) << 3);

    const int c0 = tid, c1 = tid + 512;
    const size_t bg0 = (size_t)(nc + (c0 >> 2)) * HID + ((c0 & 3) << 3);
    const size_t bg1 = (size_t)(nc + (c1 >> 2)) * HID + ((c1 & 3) << 3);

    const int mh = (w >> 2) * 64;
    const int nqw = (w & 3) * 64;
    const int c16 = lane & 15;
    const int quad = lane >> 4;
    const __bf16* blp = Bl + (size_t)(nc + nqw + c16) * HID + quad * 8;

    f32x4 acc[4][4] = {};

    for (int k0 = 0; k0 < HID; k0 += 32) {
        gload_lds16(hsrc + ag + k0, &lA[tid * 8]);
        gload_lds16(Bh + bg0 + k0, &lB[c0 * 8]);
        gload_lds16(Bh + bg1 + k0, &lB[c1 * 8]);
        __syncthreads();

        bf16x8 bl4[4];
        #pragma unroll
        for (int j = 0; j < 4; ++j)
            bl4[j] = *(const bf16x8*)(blp + (size_t)(j * 16) * HID + k0);

        bf16x8 ah[4];
        #pragma unroll
        for (int i = 0; i < 4; ++i)
            ah[i] = *(const bf16x8*)&lA[(mh + i * 16 + c16) * 32 + quad * 8];

        #pragma unroll
        for (int j = 0; j < 4; ++j) {
            bf16x8 bh = *(const bf16x8*)&lB[(nqw + j * 16 + c16) * 32 + quad * 8];
            #pragma unroll
            for (int i = 0; i < 4; ++i) {
                acc[i][j] = __builtin_amdgcn_mfma_f32_16x16x32_bf16(ah[i], bh, acc[i][j], 0, 0, 0);
                acc[i][j] = __builtin_amdgcn_mfma_f32_16x16x32_bf16(ah[i], bl4[j], acc[i][j], 0, 0, 0);
            }
        }
        __syncthreads();
    }

    #pragma unroll
    for (int j = 0; j < 4; ++j) {
        const int gcol = nc + nqw + j * 16 + c16;
        #pragma unroll
        for (int i = 0; i < 4; ++i) {
            const int growb = m0 + mh + i * 16 + quad * 4;
            #pragma unroll
            for (int rr = 0; rr < 4; ++rr) {
                const int grow = growb + rr;
                if (grow < M)
                    g[(size_t)grow * HID + gcol] = rtne(acc[i][j][rr]);
            }
        }
    }
}

// In-place-safe conv GEMM (r6 structure, ROW-MAJOR state): 1024 thr /
// BM=128 / BN=512, BK=32, single-buffer 2-barrier. Block owns all cols of
// its rows -> src == dst race-free. r9's BK=64+swizzle regressed (conflicts
// ->0 but FETCH/WRITE up ~2x, 243us) -> reverted.
__global__ __launch_bounds__(1024) void gemmg1024(
    const __bf16* __restrict__ hsrc, const __bf16* __restrict__ Bh,
    const __bf16* __restrict__ Bl, __bf16* __restrict__ g, int M)
{
    __shared__ __bf16 lA[128 * 32];   //  8KB
    __shared__ __bf16 lB[512 * 32];   // 32KB

    const int m0 = blockIdx.x * 128;
    const int tid = threadIdx.x;
    const int w = tid >> 6;
    const int lane = tid & 63;

    const bool astage = (tid < 512);
    const int ac = tid & 511;
    int arow = m0 + (ac >> 2); if (arow >= M) arow = M - 1;
    const size_t ag = (size_t)arow * HID + ((ac & 3) << 3);

    const size_t bg0 = (size_t)(tid >> 2) * HID + ((tid & 3) << 3);
    const size_t bg1 = (size_t)((tid + 1024) >> 2) * HID + (((tid + 1024) & 3) << 3);

    const int mh = (w >> 3) * 64;
    const int nq = (w & 7) * 64;
    const int c16 = lane & 15;
    const int quad = lane >> 4;
    const __bf16* blp = Bl + (size_t)(nq + c16) * HID + quad * 8;

    f32x4 acc[4][4] = {};

    for (int k0 = 0; k0 < HID; k0 += 32) {
        if (astage)
            gload_lds16(hsrc + ag + k0, &lA[ac * 8]);
        gload_lds16(Bh + bg0 + k0, &lB[tid * 8]);
        gload_lds16(Bh + bg1 + k0, &lB[(tid + 1024) * 8]);
        __syncthreads();

        bf16x8 bl4[4];
        #pragma unroll
        for (int j = 0; j < 4; ++j)
            bl4[j] = *(const bf16x8*)(blp + (size_t)(j * 16) * HID + k0);

        bf16x8 ah[4];
        #pragma unroll
        for (int i = 0; i < 4; ++i)
            ah[i] = *(const bf16x8*)&lA[(mh + i * 16 + c16) * 32 + quad * 8];

        #pragma unroll
        for (int j = 0; j < 4; ++j) {
            bf16x8 bh = *(const bf16x8*)&lB[(nq + j * 16 + c16) * 32 + quad * 8];
            #pragma unroll
            for (int i = 0; i < 4; ++i) {
                acc[i][j] = __builtin_amdgcn_mfma_f32_16x16x32_bf16(ah[i], bh, acc[i][j], 0, 0, 0);
                acc[i][j] = __builtin_amdgcn_mfma_f32_16x16x32_bf16(ah[i], bl4[j], acc[i][j], 0, 0, 0);
            }
        }
        __syncthreads();
    }

    #pragma unroll
    for (int j = 0; j < 4; ++j) {
        const int gcol = nq + j * 16 + c16;
        #pragma unroll
        for (int i = 0; i < 4; ++i) {
            const int growb = m0 + mh + i * 16 + quad * 4;
            #pragma unroll
            for (int rr = 0; rr < 4; ++rr) {
                const int grow = growb + rr;
                if (grow < M)
                    g[(size_t)grow * HID + gcol] = rtne(acc[i][j][rr]);
            }
        }
    }
}

// h[e] = relu(gs[row[e]] - g[e^1] + b + h0[e]); ROW-MAJOR. One thread per
// (edge-pair, 8-col chunk); a wave = one pair -> every stream (g e0/e1,
// h0 e0/e1, gs rows) is a contiguous 1KB wave read. In-place on g.
__global__ __launch_bounds__(256) void combine_msg(
    const __bf16* __restrict__ g, const __bf16* __restrict__ gs,
    const int* __restrict__ row, const void* __restrict__ bias, int bias_off,
    const __bf16* __restrict__ h0, __bf16* __restrict__ hdst,
    const int* __restrict__ flags)
{
    long idx = (long)blockIdx.x * 256 + threadIdx.x;
    if (idx >= (long)(E_EDGES / 2) * 64) return;
    const int p = (int)(idx >> 6);
    const int k = (int)(idx & 63) * 8;
    const int e0 = 2 * p, e1 = 2 * p + 1;
    const int u0 = row[e0], u1 = row[e1];

    bf16x8 g0 = *(const bf16x8*)(g + (size_t)e0 * HID + k);
    bf16x8 g1 = *(const bf16x8*)(g + (size_t)e1 * HID + k);
    bf16x8 r0 = *(const bf16x8*)(h0 + (size_t)e0 * HID + k);
    bf16x8 r1 = *(const bf16x8*)(h0 + (size_t)e1 * HID + k);
    bf16x8 s0 = *(const bf16x8*)(gs + (size_t)u0 * HID + k);
    bf16x8 s1 = *(const bf16x8*)(gs + (size_t)u1 * HID + k);

    const int f32 = flags[0];
    bf16x8 o0, o1;
    #pragma unroll
    for (int j = 0; j < 8; ++j) {
        const float bv = ldf(bias, bias_off + k + j, f32);
        float v0 = (float)s0[j] - (float)g1[j] + bv + (float)r0[j];
        float v1 = (float)s1[j] - (float)g0[j] + bv + (float)r1[j];
        o0[j] = rtne(v0 > 0.f ? v0 : 0.f);
        o1[j] = rtne(v1 > 0.f ? v1 : 0.f);
    }
    *(bf16x8*)(hdst + (size_t)e0 * HID + k) = o0;
    *(bf16x8*)(hdst + (size_t)e1 * HID + k) = o1;
}

__global__ void bucket_build(const int* __restrict__ col, int* __restrict__ counts,
                             int* __restrict__ buckets, int E)
{
    int e = blockIdx.x * 256 + threadIdx.x;
    if (e >= E) return;
    int c = col[e];
    int p = atomicAdd(&counts[c], 1);
    if (p < CAP) buckets[(size_t)c * CAP + p] = e;
}

// Vectorized segsum, ROW-MAJOR input [E][512]: one thread per (node, 8-col
// chunk); a wave (= one node) reads a contiguous 1KB line per bucket edge.
__global__ __launch_bounds__(256) void segsum8(
    const __bf16* __restrict__ h, const int* __restrict__ counts,
    const int* __restrict__ buckets, __bf16* __restrict__ abf,
    float* __restrict__ af32)
{
    const int nid = blockIdx.x * 4 + (threadIdx.x >> 6);
    const int fc = threadIdx.x & 63;
    if (nid >= N_NODES) return;
    const int k = fc * 8;
    int cnt = counts[nid]; if (cnt > CAP) cnt = CAP;
    const int* bl = buckets + (size_t)nid * CAP;
    float s[8] = {0.f, 0.f, 0.f, 0.f, 0.f, 0.f, 0.f, 0.f};
    for (int i = 0; i < cnt; ++i) {
        const int e = bl[i];
        bf16x8 v = *(const bf16x8*)(h + (size_t)e * HID + k);
        #pragma unroll
        for (int j = 0; j < 8; ++j) s[j] += (float)v[j];
    }
    if (af32) {
        f32x4* out = (f32x4*)(af32 + (size_t)nid * HID + k);
        out[0] = f32x4{s[0], s[1], s[2], s[3]};
        out[1] = f32x4{s[4], s[5], s[6], s[7]};
    } else {
        bf16x8 o;
        #pragma unroll
        for (int j = 0; j < 8; ++j) o[j] = rtne(s[j]);
        *(bf16x8*)(abf + (size_t)nid * HID + k) = o;
    }
}

__global__ void graph_starts(const int* __restrict__ batch, int* __restrict__ gstart, int N, int G)
{
    int n = blockIdx.x * 256 + threadIdx.x;
    if (n >= N) return;
    int b = batch[n];
    if (n == 0) {
        for (int g = 0; g <= b; ++g) gstart[g] = 0;
    } else {
        int pb = batch[n - 1];
        for (int g = pb + 1; g <= b; ++g) gstart[g] = n;
    }
    if (n == N - 1) {
        for (int g = b + 1; g <= G; ++g) gstart[g] = N;
    }
}

__global__ void pool_nodes(const float* __restrict__ hn, const int* __restrict__ gstart,
                           float* __restrict__ Apool)
{
    int g = blockIdx.x;
    int s = gstart[g], e = gstart[g + 1];
    for (int f = threadIdx.x; f < HID; f += 256) {
        float acc = 0.f;
        for (int n = s; n < e; ++n) acc += hn[(size_t)n * HID + f];
        Apool[(size_t)g * HID + f] = acc;
    }
}

// fused ffn: per block 8 graphs; t = relu(Apool@W1+b1); out = t@W2 + b2 (all f32)
__global__ __launch_bounds__(256) void ffn_fused(
    const float* __restrict__ Apool, const void* __restrict__ W1,
    const void* __restrict__ b1, const void* __restrict__ W2,
    const void* __restrict__ b2v, void* __restrict__ outv,
    const int* __restrict__ flags)
{
    __shared__ float sA[8][512];
    __shared__ float t[8][512];
    __shared__ float sW2[512];
    __shared__ float red[4];
    const int tid = threadIdx.x;
    const int g0 = blockIdx.x * 8;
    const int f32 = flags[0];

    for (int i = tid; i < 4096; i += 256)
        sA[i >> 9][i & 511] = Apool[(size_t)g0 * 512 + i];
    for (int n = tid; n < 512; n += 256)
        sW2[n] = ldf(W2, n, f32);
    __syncthreads();

    {
        float acc0[8], acc1[8];
        const float bb0 = ldf(b1, tid, f32);
        const float bb1 = ldf(b1, tid + 256, f32);
        #pragma unroll
        for (int gi = 0; gi < 8; ++gi) { acc0[gi] = bb0; acc1[gi] = bb1; }
        if (f32) {
            const float* Wf = (const float*)W1;
            for (int k = 0; k < 512; ++k) {
                float w0 = Wf[(size_t)k * 512 + tid];
                float w1 = Wf[(size_t)k * 512 + tid + 256];
                #pragma unroll
                for (int gi = 0; gi < 8; ++gi) {
                    float a = sA[gi][k];
                    acc0[gi] += a * w0;
                    acc1[gi] += a * w1;
                }
            }
        } else {
            const __bf16* Wb = (const __bf16*)W1;
            for (int k = 0; k < 512; ++k) {
                float w0 = (float)Wb[(size_t)k * 512 + tid];
                float w1 = (float)Wb[(size_t)k * 512 + tid + 256];
                #pragma unroll
                for (int gi = 0; gi < 8; ++gi) {
                    float a = sA[gi][k];
                    acc0[gi] += a * w0;
                    acc1[gi] += a * w1;
                }
            }
        }
        #pragma unroll
        for (int gi = 0; gi < 8; ++gi) {
            t[gi][tid]       = acc0[gi] > 0.f ? acc0[gi] : 0.f;
            t[gi][tid + 256] = acc1[gi] > 0.f ? acc1[gi] : 0.f;
        }
    }
    __syncthreads();

    const int lane = tid & 63;
    const int w = tid >> 6;
    const float b2 = ldf(b2v, 0, f32);
    for (int gi = 0; gi < 8; ++gi) {
        float p = t[gi][tid] * sW2[tid] + t[gi][tid + 256] * sW2[tid + 256];
        for (int o = 32; o; o >>= 1) p += __shfl_down(p, o, 64);
        if (lane == 0) red[w] = p;
        __syncthreads();
        if (tid == 0) {
            float r = red[0] + red[1] + red[2] + red[3] + b2;
            if (f32) ((float*)outv)[g0 + gi] = r;
            else     ((__bf16*)outv)[g0 + gi] = rtne(r);
        }
        __syncthreads();
    }
}

extern "C" void kernel_launch(void* const* d_in, const int* in_sizes, int n_in,
                              void* d_out, int out_size, void* d_ws, size_t ws_size,
                              hipStream_t stream)
{
    const int E = E_EDGES, NN = N_NODES, G = N_GRAPHS;

    char* wsp = (char*)d_ws;
    size_t off = 0;
    auto carve = [&](size_t bytes) -> void* {
        void* p = wsp + off;
        off += (bytes + 511) & ~(size_t)511;
        return p;
    };

    // r6 carve order (r8's reordering regressed via placement effects).
    __bf16* h0    = (__bf16*)carve((size_t)E * HID * 2);   // ROW-MAJOR [E][512]
    __bf16* h     = (__bf16*)carve((size_t)E * HID * 2);   // ROW-MAJOR layer state
    __bf16* abuf  = (__bf16*)carve((size_t)NN * HID * 2);  // row-major; gs each layer
    float*  Apool = (float*) carve((size_t)G * HID * 4);
    __bf16* WTih  = (__bf16*)carve((size_t)512 * 160 * 2);
    __bf16* WTil  = (__bf16*)carve((size_t)512 * 160 * 2);
    __bf16* WTch  = (__bf16*)carve((size_t)4 * 512 * 512 * 2);
    __bf16* WTcl  = (__bf16*)carve((size_t)4 * 512 * 512 * 2);
    __bf16* WTqh  = (__bf16*)carve((size_t)512 * 672 * 2);
    __bf16* WTql  = (__bf16*)carve((size_t)512 * 672 * 2);
    int*    ei32  = (int*)   carve((size_t)2 * E * 4);
    int*    b32   = (int*)   carve((size_t)NN * 4);
    int*    counts= (int*)   carve((size_t)NN * 4);
    int*    bucket= (int*)   carve((size_t)NN * CAP * 4);
    int*    gstart= (int*)   carve((size_t)(G + 1) * 4);
    int*    flags = (int*)   carve(2 * 4);

    // aliases into provably-dead regions
    __bf16* Aih = h;                              // E*160 bf16; h dead until layer-0 output
    __bf16* Ail = h + (size_t)E * 160;
    __bf16* Aqh = h;                              // h dead after final segsum
    __bf16* Aql = h + (size_t)NN * 672;
    float*  hn   = (float*)h0;                    // NN*512 f32; h0 dead after layer-3 combine
    float*  sfin = (float*)((char*)h0 + (size_t)NN * HID * 4);  // NN*512 f32 (row-major)

    if (off > ws_size) {  // clean fail instead of faulting
        hipMemsetAsync(d_out, 0, (size_t)out_size * 4, stream);
        return;
    }

    auto cdiv = [](long a, long b) { return (int)((a + b - 1) / b); };

    probe_dtypes<<<1, 256, 0, stream>>>((const unsigned*)d_in[0], (const unsigned*)d_in[1], flags);
    to_int32<<<cdiv((long)2 * E, 256), 256, 0, stream>>>(d_in[1], ei32, (long)2 * E, flags);
    to_int32<<<cdiv(NN, 256), 256, 0, stream>>>(d_in[3], b32, NN, flags);

    const int* row = ei32;
    const int* col = ei32 + E;

    hipMemsetAsync(counts, 0, (size_t)NN * 4, stream);

    split_transpose_t<<<dim3(8, 3, 1), 256, 0, stream>>>(d_in[4], WTih, WTil, 147, 512, 160, 0, flags);
    split_transpose_t<<<dim3(8, 8, 4), 256, 0, stream>>>(d_in[6], WTch, WTcl, 512, 512, 512, 0, flags);
    split_transpose_t<<<dim3(8, 11, 1), 256, 0, stream>>>(d_in[8], WTqh, WTql, 645, 512, 672, 0, flags);

    bucket_build<<<cdiv(E, 256), 256, 0, stream>>>(col, counts, bucket, E);

    // edge init: h0 = relu([x[row], ea] @ W_ei + b_ei) -> ROW-MAJOR (kmaj=0)
    build_Ainit_split8<<<cdiv((long)E * 20, 256), 256, 0, stream>>>(d_in[0], d_in[2], row, Aih, Ail, flags);
    gemm3w<<<cdiv(E, 128), 1024, 0, stream>>>(Aih, Ail, WTih, WTil, d_in[5], h0, 0, 0, E, 160, flags);

    // DMPNN layers: g = h@W; gs = segsum(g); h = relu(gs[row] - g[rev] + b + h0)
    const long ncomb = (long)(E / 2) * 64;
    for (int l = 0; l < 4; ++l) {
        const __bf16* Wh = WTch + (size_t)l * 512 * 512;
        const __bf16* Wl = WTcl + (size_t)l * 512 * 512;
        if (l == 0)   // h0 -> h: src != dst, col-split 2-blocks/CU
            gemmg512<<<dim3(cdiv(E, 128), 2), 512, 0, stream>>>(h0, Wh, Wl, h, E);
        else          // h -> h in-place (block owns all cols of its rows)
            gemmg1024<<<cdiv(E, 128), 1024, 0, stream>>>(h, Wh, Wl, h, E);
        segsum8<<<cdiv(NN, 4), 256, 0, stream>>>(h, counts, bucket, abuf, nullptr);
        combine_msg<<<cdiv(ncomb, 256), 256, 0, stream>>>(h, abuf, row, d_in[7], l * 512, h0, h, flags);
    }

    // final aggregation (f32, row-major out) + e2n (wide 3-term GEMM, f32 row-major out)
    segsum8<<<cdiv(NN, 4), 256, 0, stream>>>(h, counts, bucket, nullptr, sfin);
    build_Ae2n_split8<<<cdiv((long)NN * 84, 256), 256, 0, stream>>>(d_in[0], sfin, Aqh, Aql, flags);
    gemm3w<<<cdiv(NN, 128), 1024, 0, stream>>>(Aqh, Aql, WTqh, WTql, d_in[9], hn, 1, 0, NN, 672, flags);

    // pool + fused ffn (all f32)
    graph_starts<<<cdiv(NN, 256), 256, 0, stream>>>(b32, gstart, NN, G);
    pool_nodes<<<G, 256, 0, stream>>>(hn, gstart, Apool);
    ffn_fused<<<G / 8, 256, 0, stream>>>(Apool, d_in[10], d_in[11], d_in[12], d_in[13], d_out, flags);
}

// Round 11
// 1313.884 us; speedup vs baseline: 1.3935x; 1.2282x over previous
//
#include <hip/hip_runtime.h>

typedef __bf16 bf16x8 __attribute__((ext_vector_type(8)));
typedef float  f32x4  __attribute__((ext_vector_type(4)));

#define E_EDGES 100000
#define N_NODES 25000
#define N_GRAPHS 2048
#define HID 512
#define CAP 32

__device__ __forceinline__ void gload_lds16(const void* g, void* l) {
    __builtin_amdgcn_global_load_lds(
        (const __attribute__((address_space(1))) void*)g,
        (__attribute__((address_space(3))) void*)l, 16, 0, 0);
}

__device__ __forceinline__ __bf16 rtne(float x) {
    union { unsigned short s; __bf16 b; } u;
    unsigned v = __float_as_uint(x);
    u.s = (unsigned short)((v + 0x7FFF + ((v >> 16) & 1)) >> 16);
    return u.b;
}

__device__ __forceinline__ void split2(float x, __bf16& hi, __bf16& lo) {
    hi = rtne(x);
    lo = rtne(x - (float)hi);
}

__device__ __forceinline__ float ldf(const void* p, long i, int f32) {
    return f32 ? ((const float*)p)[i] : (float)(((const __bf16*)p)[i]);
}

// flags[0]=1 if float inputs are f32 (else bf16); flags[1]=1 if int inputs are i64
__global__ void probe_dtypes(const unsigned* __restrict__ xr, const unsigned* __restrict__ eir,
                             int* __restrict__ flags)
{
    __shared__ int cfp, ci;
    if (threadIdx.x == 0) { cfp = 0; ci = 0; }
    __syncthreads();
    int lc = 0;
    for (int i = threadIdx.x; i < 1024; i += 256) {
        unsigned elo = (xr[i] >> 7) & 0xFFu;
        if (elo > 140u) lc++;
    }
    atomicAdd(&cfp, lc);
    int ln = 0;
    for (int i = threadIdx.x; i < 512; i += 256) {
        if (eir[2 * i + 1] != 0u) ln++;
    }
    atomicAdd(&ci, ln);
    __syncthreads();
    if (threadIdx.x == 0) {
        flags[0] = (cfp > 100) ? 1 : 0;
        flags[1] = (ci < 256) ? 1 : 0;
    }
}

__global__ void to_int32(const void* __restrict__ src, int* __restrict__ dst, long n,
                         const int* __restrict__ flags)
{
    long i = (long)blockIdx.x * 256 + threadIdx.x;
    if (i >= n) return;
    dst[i] = flags[1] ? (int)((const long long*)src)[i] : ((const int*)src)[i];
}

// Tiled transpose+split: WThi/WTlo[n,k] = split(W[krow0 + z*512 + k, n]), zero-pad to Kpad.
__global__ __launch_bounds__(256) void split_transpose_t(
    const void* __restrict__ W, __bf16* __restrict__ Whi, __bf16* __restrict__ Wlo,
    int Ksrc, int N, int Kpad, int krow0, const int* __restrict__ flags)
{
    __shared__ float tile[64][65];
    const int z = blockIdx.z;
    const int nb = blockIdx.x * 64;
    const int kb = blockIdx.y * 64;
    const int f32m = flags[0];
    const int lx = threadIdx.x & 63;
    const size_t dsto = (size_t)z * N * Kpad;
    const int kro = krow0 + z * 512;

    for (int rr = threadIdx.x >> 6; rr < 64; rr += 4) {
        const int k = kb + rr;
        const int n = nb + lx;
        float v = 0.f;
        if (k < Ksrc && n < N) v = ldf(W, (size_t)(kro + k) * N + n, f32m);
        tile[rr][lx] = v;
    }
    __syncthreads();
    for (int rr = threadIdx.x >> 6; rr < 64; rr += 4) {
        const int n = nb + rr;
        const int k = kb + lx;
        if (n < N && k < Kpad) {
            __bf16 hi, lo; split2(tile[lx][rr], hi, lo);
            Whi[dsto + (size_t)n * Kpad + k] = hi;
            Wlo[dsto + (size_t)n * Kpad + k] = lo;
        }
    }
}

// A_init[e,0:160] = [x[row[e],0:133], ea[e,0:14], 0] -> hi/lo; one thread per 8-f chunk
__global__ void build_Ainit_split8(const void* __restrict__ x, const void* __restrict__ ea,
                                   const int* __restrict__ row, __bf16* __restrict__ Ah,
                                   __bf16* __restrict__ Al, const int* __restrict__ flags)
{
    long idx = (long)blockIdx.x * 256 + threadIdx.x;
    if (idx >= (long)E_EDGES * 20) return;
    const int e = (int)(idx / 20), c = (int)(idx % 20);
    const int f0 = c * 8;
    const int f32m = flags[0];
    const int r = row[e];
    bf16x8 oh, ol;
    #pragma unroll
    for (int j = 0; j < 8; ++j) {
        const int f = f0 + j;
        float v = 0.f;
        if (f < 133)      v = ldf(x, (size_t)r * 133 + f, f32m);
        else if (f < 147) v = ldf(ea, (size_t)e * 14 + (f - 133), f32m);
        __bf16 hi, lo; split2(v, hi, lo);
        oh[j] = hi; ol[j] = lo;
    }
    *(bf16x8*)(Ah + (size_t)e * 160 + f0) = oh;
    *(bf16x8*)(Al + (size_t)e * 160 + f0) = ol;
}

// A_e2n[n,0:672] = [x[n,0:133], s_f32[n,0:512], 0] -> hi/lo; one thread per 8-f chunk
__global__ void build_Ae2n_split8(const void* __restrict__ x, const float* __restrict__ s,
                                  __bf16* __restrict__ Ah, __bf16* __restrict__ Al,
                                  const int* __restrict__ flags)
{
    long idx = (long)blockIdx.x * 256 + threadIdx.x;
    if (idx >= (long)N_NODES * 84) return;
    const int n = (int)(idx / 84), c = (int)(idx % 84);
    const int f0 = c * 8;
    const int f32m = flags[0];
    bf16x8 oh, ol;
    #pragma unroll
    for (int j = 0; j < 8; ++j) {
        const int f = f0 + j;
        float v = 0.f;
        if (f < 133)      v = ldf(x, (size_t)n * 133 + f, f32m);
        else if (f < 645) v = s[(size_t)n * HID + (f - 133)];
        __bf16 hi, lo; split2(v, hi, lo);
        oh[j] = hi; ol[j] = lo;
    }
    *(bf16x8*)(Ah + (size_t)n * 672 + f0) = oh;
    *(bf16x8*)(Al + (size_t)n * 672 + f0) = ol;
}

// Wide split-precision GEMM: C[M,512] = relu(A @ BT^T + bias), 3-term MFMA.
// Kept full-precision: edge-init (f32 inputs) and e2n (feeds pooled output).
__global__ __launch_bounds__(1024) void gemm3w(
    const __bf16* __restrict__ Ah, const __bf16* __restrict__ Al,
    const __bf16* __restrict__ Bh, const __bf16* __restrict__ Bl,
    const void* __restrict__ bias,
    void* __restrict__ C, int out_f32, int kmaj, int M, int K, const int* __restrict__ flags)
{
    __shared__ __bf16 lAh[128 * 32];
    __shared__ __bf16 lAl[128 * 32];
    __shared__ __bf16 lBh[512 * 32];

    const int m0 = blockIdx.x * 128;
    const int tid = threadIdx.x;
    const int w = tid >> 6;
    const int lane = tid & 63;

    const int ac = tid & 511;
    int arow = m0 + (ac >> 2); if (arow >= M) arow = M - 1;
    const int akc = (ac & 3) << 3;
    const __bf16* Asrc = (tid < 512) ? Ah : Al;
    const size_t ag = (size_t)arow * K + akc;
    __bf16* aw = ((tid < 512) ? lAh : lAl) + (ac >> 2) * 32 + akc;

    const size_t bg0 = (size_t)(tid >> 2) * K + ((tid & 3) << 3);
    const size_t bg1 = (size_t)((tid + 1024) >> 2) * K + (((tid + 1024) & 3) << 3);
    __bf16* wB0 = lBh + (size_t)tid * 8;
    __bf16* wB1 = lBh + (size_t)(tid + 1024) * 8;

    const int mh = (w >> 3) * 64;
    const int nq = (w & 7) * 64;
    const int c16 = lane & 15;
    const int quad = lane >> 4;

    const __bf16* blp = Bl + (size_t)(nq + c16) * K + quad * 8;

    f32x4 acc[4][4] = {};

    for (int k0 = 0; k0 < K; k0 += 32) {
        gload_lds16(Asrc + ag + k0, aw);
        gload_lds16(Bh + bg0 + k0, wB0);
        gload_lds16(Bh + bg1 + k0, wB1);
        __syncthreads();

        bf16x8 bl[4];
        #pragma unroll
        for (int j = 0; j < 4; ++j)
            bl[j] = *(const bf16x8*)(blp + (size_t)(j * 16) * K + k0);

        bf16x8 ah[4], al[4];
        #pragma unroll
        for (int i = 0; i < 4; ++i) {
            ah[i] = *(const bf16x8*)(lAh + (mh + i * 16 + c16) * 32 + quad * 8);
            al[i] = *(const bf16x8*)(lAl + (mh + i * 16 + c16) * 32 + quad * 8);
        }
        #pragma unroll
        for (int j = 0; j < 4; ++j) {
            bf16x8 bh = *(const bf16x8*)(lBh + (nq + j * 16 + c16) * 32 + quad * 8);
            #pragma unroll
            for (int i = 0; i < 4; ++i) {
                acc[i][j] = __builtin_amdgcn_mfma_f32_16x16x32_bf16(ah[i], bh, acc[i][j], 0, 0, 0);
                acc[i][j] = __builtin_amdgcn_mfma_f32_16x16x32_bf16(al[i], bh, acc[i][j], 0, 0, 0);
                acc[i][j] = __builtin_amdgcn_mfma_f32_16x16x32_bf16(ah[i], bl[j], acc[i][j], 0, 0, 0);
            }
        }
        __syncthreads();
    }

    const int f32 = flags[0];
    const size_t kstride = (size_t)M * 32;
    #pragma unroll
    for (int j = 0; j < 4; ++j) {
        const int gcol = nq + j * 16 + c16;
        const float bv = ldf(bias, gcol, f32);
        #pragma unroll
        for (int i = 0; i < 4; ++i) {
            const int growb = m0 + mh + i * 16 + quad * 4;
            #pragma unroll
            for (int rr = 0; rr < 4; ++rr) {
                const int grow = growb + rr;
                if (grow < M) {
                    float v = acc[i][j][rr] + bv;
                    v = v > 0.f ? v : 0.f;
                    if (out_f32)   ((float*)C)[(size_t)grow * HID + gcol] = v;
                    else if (kmaj) ((__bf16*)C)[(size_t)(gcol >> 5) * kstride + (size_t)grow * 32 + (gcol & 31)] = rtne(v);
                    else           ((__bf16*)C)[(size_t)grow * HID + gcol] = rtne(v);
                }
            }
        }
    }
}

// Streaming GEMM g = h @ Wh^T, 1-TERM (r11): A (=h) is exactly bf16, so the
// only precision loss vs 2-term is weight rounding (2^-9 rel) — subdominant
// to h's own bf16 storage error. Removes the per-K-step bl4 global loads
// (one exposed L2 round-trip) and half the MFMA issue. ROW-MAJOR [E][512].
// 512-thr / BM=128 / BN=256 col-split: 2 blocks/CU. REQUIRES src != dst.
__global__ __launch_bounds__(512, 4) void gemmg512(
    const __bf16* __restrict__ hsrc, const __bf16* __restrict__ Bh,
    __bf16* __restrict__ g, int M)
{
    __shared__ __bf16 lA[128 * 32];   //  8KB
    __shared__ __bf16 lB[256 * 32];   // 16KB

    const int m0 = blockIdx.x * 128;
    const int nc = blockIdx.y * 256;
    const int tid = threadIdx.x;
    const int w = tid >> 6;
    const int lane = tid & 63;

    int arow = m0 + (tid >> 2); if (arow >= M) arow = M - 1;
    const size_t ag = (size_t)arow * HID + ((tid & 3) << 3);

    const int c0 = tid, c1 = tid + 512;
    const size_t bg0 = (size_t)(nc + (c0 >> 2)) * HID + ((c0 & 3) << 3);
    const size_t bg1 = (size_t)(nc + (c1 >> 2)) * HID + ((c1 & 3) << 3);

    const int mh = (w >> 2) * 64;
    const int nqw = (w & 3) * 64;
    const int c16 = lane & 15;
    const int quad = lane >> 4;

    f32x4 acc[4][4] = {};

    for (int k0 = 0; k0 < HID; k0 += 32) {
        gload_lds16(hsrc + ag + k0, &lA[tid * 8]);
        gload_lds16(Bh + bg0 + k0, &lB[c0 * 8]);
        gload_lds16(Bh + bg1 + k0, &lB[c1 * 8]);
        __syncthreads();

        bf16x8 ah[4];
        #pragma unroll
        for (int i = 0; i < 4; ++i)
            ah[i] = *(const bf16x8*)&lA[(mh + i * 16 + c16) * 32 + quad * 8];

        #pragma unroll
        for (int j = 0; j < 4; ++j) {
            bf16x8 bh = *(const bf16x8*)&lB[(nqw + j * 16 + c16) * 32 + quad * 8];
            #pragma unroll
            for (int i = 0; i < 4; ++i)
                acc[i][j] = __builtin_amdgcn_mfma_f32_16x16x32_bf16(ah[i], bh, acc[i][j], 0, 0, 0);
        }
        __syncthreads();
    }

    #pragma unroll
    for (int j = 0; j < 4; ++j) {
        const int gcol = nc + nqw + j * 16 + c16;
        #pragma unroll
        for (int i = 0; i < 4; ++i) {
            const int growb = m0 + mh + i * 16 + quad * 4;
            #pragma unroll
            for (int rr = 0; rr < 4; ++rr) {
                const int grow = growb + rr;
                if (grow < M)
                    g[(size_t)grow * HID + gcol] = rtne(acc[i][j][rr]);
            }
        }
    }
}

// In-place-safe conv GEMM, 1-TERM (r11; see gemmg512 note). 1024 thr /
// BM=128 / BN=512, BK=32, single-buffer 2-barrier. Block owns all cols of
// its rows -> src == dst race-free.
__global__ __launch_bounds__(1024) void gemmg1024(
    const __bf16* __restrict__ hsrc, const __bf16* __restrict__ Bh,
    __bf16* __restrict__ g, int M)
{
    __shared__ __bf16 lA[128 * 32];   //  8KB
    __shared__ __bf16 lB[512 * 32];   // 32KB

    const int m0 = blockIdx.x * 128;
    const int tid = threadIdx.x;
    const int w = tid >> 6;
    const int lane = tid & 63;

    const bool astage = (tid < 512);
    const int ac = tid & 511;
    int arow = m0 + (ac >> 2); if (arow >= M) arow = M - 1;
    const size_t ag = (size_t)arow * HID + ((ac & 3) << 3);

    const size_t bg0 = (size_t)(tid >> 2) * HID + ((tid & 3) << 3);
    const size_t bg1 = (size_t)((tid + 1024) >> 2) * HID + (((tid + 1024) & 3) << 3);

    const int mh = (w >> 3) * 64;
    const int nq = (w & 7) * 64;
    const int c16 = lane & 15;
    const int quad = lane >> 4;

    f32x4 acc[4][4] = {};

    for (int k0 = 0; k0 < HID; k0 += 32) {
        if (astage)
            gload_lds16(hsrc + ag + k0, &lA[ac * 8]);
        gload_lds16(Bh + bg0 + k0, &lB[tid * 8]);
        gload_lds16(Bh + bg1 + k0, &lB[(tid + 1024) * 8]);
        __syncthreads();

        bf16x8 ah[4];
        #pragma unroll
        for (int i = 0; i < 4; ++i)
            ah[i] = *(const bf16x8*)&lA[(mh + i * 16 + c16) * 32 + quad * 8];

        #pragma unroll
        for (int j = 0; j < 4; ++j) {
            bf16x8 bh = *(const bf16x8*)&lB[(nq + j * 16 + c16) * 32 + quad * 8];
            #pragma unroll
            for (int i = 0; i < 4; ++i)
                acc[i][j] = __builtin_amdgcn_mfma_f32_16x16x32_bf16(ah[i], bh, acc[i][j], 0, 0, 0);
        }
        __syncthreads();
    }

    #pragma unroll
    for (int j = 0; j < 4; ++j) {
        const int gcol = nq + j * 16 + c16;
        #pragma unroll
        for (int i = 0; i < 4; ++i) {
            const int growb = m0 + mh + i * 16 + quad * 4;
            #pragma unroll
            for (int rr = 0; rr < 4; ++rr) {
                const int grow = growb + rr;
                if (grow < M)
                    g[(size_t)grow * HID + gcol] = rtne(acc[i][j][rr]);
            }
        }
    }
}

// h[e] = relu(gs[row[e]] - g[e^1] + b + h0[e]); ROW-MAJOR. One thread per
// (edge-pair, 8-col chunk); a wave = one pair -> contiguous 1KB wave reads.
__global__ __launch_bounds__(256) void combine_msg(
    const __bf16* __restrict__ g, const __bf16* __restrict__ gs,
    const int* __restrict__ row, const void* __restrict__ bias, int bias_off,
    const __bf16* __restrict__ h0, __bf16* __restrict__ hdst,
    const int* __restrict__ flags)
{
    long idx = (long)blockIdx.x * 256 + threadIdx.x;
    if (idx >= (long)(E_EDGES / 2) * 64) return;
    const int p = (int)(idx >> 6);
    const int k = (int)(idx & 63) * 8;
    const int e0 = 2 * p, e1 = 2 * p + 1;
    const int u0 = row[e0], u1 = row[e1];

    bf16x8 g0 = *(const bf16x8*)(g + (size_t)e0 * HID + k);
    bf16x8 g1 = *(const bf16x8*)(g + (size_t)e1 * HID + k);
    bf16x8 r0 = *(const bf16x8*)(h0 + (size_t)e0 * HID + k);
    bf16x8 r1 = *(const bf16x8*)(h0 + (size_t)e1 * HID + k);
    bf16x8 s0 = *(const bf16x8*)(gs + (size_t)u0 * HID + k);
    bf16x8 s1 = *(const bf16x8*)(gs + (size_t)u1 * HID + k);

    const int f32 = flags[0];
    bf16x8 o0, o1;
    #pragma unroll
    for (int j = 0; j < 8; ++j) {
        const float bv = ldf(bias, bias_off + k + j, f32);
        float v0 = (float)s0[j] - (float)g1[j] + bv + (float)r0[j];
        float v1 = (float)s1[j] - (float)g0[j] + bv + (float)r1[j];
        o0[j] = rtne(v0 > 0.f ? v0 : 0.f);
        o1[j] = rtne(v1 > 0.f ? v1 : 0.f);
    }
    *(bf16x8*)(hdst + (size_t)e0 * HID + k) = o0;
    *(bf16x8*)(hdst + (size_t)e1 * HID + k) = o1;
}

__global__ void bucket_build(const int* __restrict__ col, int* __restrict__ counts,
                             int* __restrict__ buckets, int E)
{
    int e = blockIdx.x * 256 + threadIdx.x;
    if (e >= E) return;
    int c = col[e];
    int p = atomicAdd(&counts[c], 1);
    if (p < CAP) buckets[(size_t)c * CAP + p] = e;
}

// Vectorized segsum, ROW-MAJOR input [E][512]: one thread per (node, 8-col
// chunk); a wave (= one node) reads a contiguous 1KB line per bucket edge.
__global__ __launch_bounds__(256) void segsum8(
    const __bf16* __restrict__ h, const int* __restrict__ counts,
    const int* __restrict__ buckets, __bf16* __restrict__ abf,
    float* __restrict__ af32)
{
    const int nid = blockIdx.x * 4 + (threadIdx.x >> 6);
    const int fc = threadIdx.x & 63;
    if (nid >= N_NODES) return;
    const int k = fc * 8;
    int cnt = counts[nid]; if (cnt > CAP) cnt = CAP;
    const int* bl = buckets + (size_t)nid * CAP;
    float s[8] = {0.f, 0.f, 0.f, 0.f, 0.f, 0.f, 0.f, 0.f};
    for (int i = 0; i < cnt; ++i) {
        const int e = bl[i];
        bf16x8 v = *(const bf16x8*)(h + (size_t)e * HID + k);
        #pragma unroll
        for (int j = 0; j < 8; ++j) s[j] += (float)v[j];
    }
    if (af32) {
        f32x4* out = (f32x4*)(af32 + (size_t)nid * HID + k);
        out[0] = f32x4{s[0], s[1], s[2], s[3]};
        out[1] = f32x4{s[4], s[5], s[6], s[7]};
    } else {
        bf16x8 o;
        #pragma unroll
        for (int j = 0; j < 8; ++j) o[j] = rtne(s[j]);
        *(bf16x8*)(abf + (size_t)nid * HID + k) = o;
    }
}

__global__ void graph_starts(const int* __restrict__ batch, int* __restrict__ gstart, int N, int G)
{
    int n = blockIdx.x * 256 + threadIdx.x;
    if (n >= N) return;
    int b = batch[n];
    if (n == 0) {
        for (int g = 0; g <= b; ++g) gstart[g] = 0;
    } else {
        int pb = batch[n - 1];
        for (int g = pb + 1; g <= b; ++g) gstart[g] = n;
    }
    if (n == N - 1) {
        for (int g = b + 1; g <= G; ++g) gstart[g] = N;
    }
}

__global__ void pool_nodes(const float* __restrict__ hn, const int* __restrict__ gstart,
                           float* __restrict__ Apool)
{
    int g = blockIdx.x;
    int s = gstart[g], e = gstart[g + 1];
    for (int f = threadIdx.x; f < HID; f += 256) {
        float acc = 0.f;
        for (int n = s; n < e; ++n) acc += hn[(size_t)n * HID + f];
        Apool[(size_t)g * HID + f] = acc;
    }
}

// fused ffn: per block 8 graphs; t = relu(Apool@W1+b1); out = t@W2 + b2 (all f32)
__global__ __launch_bounds__(256) void ffn_fused(
    const float* __restrict__ Apool, const void* __restrict__ W1,
    const void* __restrict__ b1, const void* __restrict__ W2,
    const void* __restrict__ b2v, void* __restrict__ outv,
    const int* __restrict__ flags)
{
    __shared__ float sA[8][512];
    __shared__ float t[8][512];
    __shared__ float sW2[512];
    __shared__ float red[4];
    const int tid = threadIdx.x;
    const int g0 = blockIdx.x * 8;
    const int f32 = flags[0];

    for (int i = tid; i < 4096; i += 256)
        sA[i >> 9][i & 511] = Apool[(size_t)g0 * 512 + i];
    for (int n = tid; n < 512; n += 256)
        sW2[n] = ldf(W2, n, f32);
    __syncthreads();

    {
        float acc0[8], acc1[8];
        const float bb0 = ldf(b1, tid, f32);
        const float bb1 = ldf(b1, tid + 256, f32);
        #pragma unroll
        for (int gi = 0; gi < 8; ++gi) { acc0[gi] = bb0; acc1[gi] = bb1; }
        if (f32) {
            const float* Wf = (const float*)W1;
            for (int k = 0; k < 512; ++k) {
                float w0 = Wf[(size_t)k * 512 + tid];
                float w1 = Wf[(size_t)k * 512 + tid + 256];
                #pragma unroll
                for (int gi = 0; gi < 8; ++gi) {
                    float a = sA[gi][k];
                    acc0[gi] += a * w0;
                    acc1[gi] += a * w1;
                }
            }
        } else {
            const __bf16* Wb = (const __bf16*)W1;
            for (int k = 0; k < 512; ++k) {
                float w0 = (float)Wb[(size_t)k * 512 + tid];
                float w1 = (float)Wb[(size_t)k * 512 + tid + 256];
                #pragma unroll
                for (int gi = 0; gi < 8; ++gi) {
                    float a = sA[gi][k];
                    acc0[gi] += a * w0;
                    acc1[gi] += a * w1;
                }
            }
        }
        #pragma unroll
        for (int gi = 0; gi < 8; ++gi) {
            t[gi][tid]       = acc0[gi] > 0.f ? acc0[gi] : 0.f;
            t[gi][tid + 256] = acc1[gi] > 0.f ? acc1[gi] : 0.f;
        }
    }
    __syncthreads();

    const int lane = tid & 63;
    const int w = tid >> 6;
    const float b2 = ldf(b2v, 0, f32);
    for (int gi = 0; gi < 8; ++gi) {
        float p = t[gi][tid] * sW2[tid] + t[gi][tid + 256] * sW2[tid + 256];
        for (int o = 32; o; o >>= 1) p += __shfl_down(p, o, 64);
        if (lane == 0) red[w] = p;
        __syncthreads();
        if (tid == 0) {
            float r = red[0] + red[1] + red[2] + red[3] + b2;
            if (f32) ((float*)outv)[g0 + gi] = r;
            else     ((__bf16*)outv)[g0 + gi] = rtne(r);
        }
        __syncthreads();
    }
}

extern "C" void kernel_launch(void* const* d_in, const int* in_sizes, int n_in,
                              void* d_out, int out_size, void* d_ws, size_t ws_size,
                              hipStream_t stream)
{
    const int E = E_EDGES, NN = N_NODES, G = N_GRAPHS;

    char* wsp = (char*)d_ws;
    size_t off = 0;
    auto carve = [&](size_t bytes) -> void* {
        void* p = wsp + off;
        off += (bytes + 511) & ~(size_t)511;
        return p;
    };

    // r6 carve order (r8's reordering regressed via placement effects).
    __bf16* h0    = (__bf16*)carve((size_t)E * HID * 2);   // ROW-MAJOR [E][512]
    __bf16* h     = (__bf16*)carve((size_t)E * HID * 2);   // ROW-MAJOR layer state
    __bf16* abuf  = (__bf16*)carve((size_t)NN * HID * 2);  // row-major; gs each layer
    float*  Apool = (float*) carve((size_t)G * HID * 4);
    __bf16* WTih  = (__bf16*)carve((size_t)512 * 160 * 2);
    __bf16* WTil  = (__bf16*)carve((size_t)512 * 160 * 2);
    __bf16* WTch  = (__bf16*)carve((size_t)4 * 512 * 512 * 2);
    __bf16* WTcl  = (__bf16*)carve((size_t)4 * 512 * 512 * 2);
    __bf16* WTqh  = (__bf16*)carve((size_t)512 * 672 * 2);
    __bf16* WTql  = (__bf16*)carve((size_t)512 * 672 * 2);
    int*    ei32  = (int*)   carve((size_t)2 * E * 4);
    int*    b32   = (int*)   carve((size_t)NN * 4);
    int*    counts= (int*)   carve((size_t)NN * 4);
    int*    bucket= (int*)   carve((size_t)NN * CAP * 4);
    int*    gstart= (int*)   carve((size_t)(G + 1) * 4);
    int*    flags = (int*)   carve(2 * 4);

    // aliases into provably-dead regions
    __bf16* Aih = h;                              // E*160 bf16; h dead until layer-0 output
    __bf16* Ail = h + (size_t)E * 160;
    __bf16* Aqh = h;                              // h dead after final segsum
    __bf16* Aql = h + (size_t)NN * 672;
    float*  hn   = (float*)h0;                    // NN*512 f32; h0 dead after layer-3 combine
    float*  sfin = (float*)((char*)h0 + (size_t)NN * HID * 4);  // NN*512 f32 (row-major)

    if (off > ws_size) {  // clean fail instead of faulting
        hipMemsetAsync(d_out, 0, (size_t)out_size * 4, stream);
        return;
    }

    auto cdiv = [](long a, long b) { return (int)((a + b - 1) / b); };

    probe_dtypes<<<1, 256, 0, stream>>>((const unsigned*)d_in[0], (const unsigned*)d_in[1], flags);
    to_int32<<<cdiv((long)2 * E, 256), 256, 0, stream>>>(d_in[1], ei32, (long)2 * E, flags);
    to_int32<<<cdiv(NN, 256), 256, 0, stream>>>(d_in[3], b32, NN, flags);

    const int* row = ei32;
    const int* col = ei32 + E;

    hipMemsetAsync(counts, 0, (size_t)NN * 4, stream);

    split_transpose_t<<<dim3(8, 3, 1), 256, 0, stream>>>(d_in[4], WTih, WTil, 147, 512, 160, 0, flags);
    split_transpose_t<<<dim3(8, 8, 4), 256, 0, stream>>>(d_in[6], WTch, WTcl, 512, 512, 512, 0, flags);
    split_transpose_t<<<dim3(8, 11, 1), 256, 0, stream>>>(d_in[8], WTqh, WTql, 645, 512, 672, 0, flags);

    bucket_build<<<cdiv(E, 256), 256, 0, stream>>>(col, counts, bucket, E);

    // edge init: h0 = relu([x[row], ea] @ W_ei + b_ei) -> ROW-MAJOR (kmaj=0, 3-term)
    build_Ainit_split8<<<cdiv((long)E * 20, 256), 256, 0, stream>>>(d_in[0], d_in[2], row, Aih, Ail, flags);
    gemm3w<<<cdiv(E, 128), 1024, 0, stream>>>(Aih, Ail, WTih, WTil, d_in[5], h0, 0, 0, E, 160, flags);

    // DMPNN layers: g = h@W (1-term); gs = segsum(g); h = relu(gs[row] - g[rev] + b + h0)
    const long ncomb = (long)(E / 2) * 64;
    for (int l = 0; l < 4; ++l) {
        const __bf16* Wh = WTch + (size_t)l * 512 * 512;
        if (l == 0)   // h0 -> h: src != dst, col-split 2-blocks/CU
            gemmg512<<<dim3(cdiv(E, 128), 2), 512, 0, stream>>>(h0, Wh, h, E);
        else          // h -> h in-place (block owns all cols of its rows)
            gemmg1024<<<cdiv(E, 128), 1024, 0, stream>>>(h, Wh, h, E);
        segsum8<<<cdiv(NN, 4), 256, 0, stream>>>(h, counts, bucket, abuf, nullptr);
        combine_msg<<<cdiv(ncomb, 256), 256, 0, stream>>>(h, abuf, row, d_in[7], l * 512, h0, h, flags);
    }

    // final aggregation (f32, row-major out) + e2n (wide 3-term GEMM, f32 row-major out)
    segsum8<<<cdiv(NN, 4), 256, 0, stream>>>(h, counts, bucket, nullptr, sfin);
    build_Ae2n_split8<<<cdiv((long)NN * 84, 256), 256, 0, stream>>>(d_in[0], sfin, Aqh, Aql, flags);
    gemm3w<<<cdiv(NN, 128), 1024, 0, stream>>>(Aqh, Aql, WTqh, WTql, d_in[9], hn, 1, 0, NN, 672, flags);

    // pool + fused ffn (all f32)
    graph_starts<<<cdiv(NN, 256), 256, 0, stream>>>(b32, gstart, NN, G);
    pool_nodes<<<G, 256, 0, stream>>>(hn, gstart, Apool);
    ffn_fused<<<G / 8, 256, 0, stream>>>(Apool, d_in[10], d_in[11], d_in[12], d_in[13], d_out, flags);
}

// Round 12
// 1310.022 us; speedup vs baseline: 1.3976x; 1.0029x over previous
//
#include <hip/hip_runtime.h>

typedef __bf16 bf16x8 __attribute__((ext_vector_type(8)));
typedef float  f32x4  __attribute__((ext_vector_type(4)));

#define E_EDGES 100000
#define N_NODES 25000
#define N_GRAPHS 2048
#define HID 512
#define CAP 32

__device__ __forceinline__ void gload_lds16(const void* g, void* l) {
    __builtin_amdgcn_global_load_lds(
        (const __attribute__((address_space(1))) void*)g,
        (__attribute__((address_space(3))) void*)l, 16, 0, 0);
}

__device__ __forceinline__ __bf16 rtne(float x) {
    union { unsigned short s; __bf16 b; } u;
    unsigned v = __float_as_uint(x);
    u.s = (unsigned short)((v + 0x7FFF + ((v >> 16) & 1)) >> 16);
    return u.b;
}

__device__ __forceinline__ void split2(float x, __bf16& hi, __bf16& lo) {
    hi = rtne(x);
    lo = rtne(x - (float)hi);
}

__device__ __forceinline__ float ldf(const void* p, long i, int f32) {
    return f32 ? ((const float*)p)[i] : (float)(((const __bf16*)p)[i]);
}

// flags[0]=1 if float inputs are f32 (else bf16); flags[1]=1 if int inputs are i64
__global__ void probe_dtypes(const unsigned* __restrict__ xr, const unsigned* __restrict__ eir,
                             int* __restrict__ flags)
{
    __shared__ int cfp, ci;
    if (threadIdx.x == 0) { cfp = 0; ci = 0; }
    __syncthreads();
    int lc = 0;
    for (int i = threadIdx.x; i < 1024; i += 256) {
        unsigned elo = (xr[i] >> 7) & 0xFFu;
        if (elo > 140u) lc++;
    }
    atomicAdd(&cfp, lc);
    int ln = 0;
    for (int i = threadIdx.x; i < 512; i += 256) {
        if (eir[2 * i + 1] != 0u) ln++;
    }
    atomicAdd(&ci, ln);
    __syncthreads();
    if (threadIdx.x == 0) {
        flags[0] = (cfp > 100) ? 1 : 0;
        flags[1] = (ci < 256) ? 1 : 0;
    }
}

__global__ void to_int32(const void* __restrict__ src, int* __restrict__ dst, long n,
                         const int* __restrict__ flags)
{
    long i = (long)blockIdx.x * 256 + threadIdx.x;
    if (i >= n) return;
    dst[i] = flags[1] ? (int)((const long long*)src)[i] : ((const int*)src)[i];
}

// Tiled transpose+split: WThi/WTlo[n,k] = split(W[krow0 + z*512 + k, n]), zero-pad to Kpad.
__global__ __launch_bounds__(256) void split_transpose_t(
    const void* __restrict__ W, __bf16* __restrict__ Whi, __bf16* __restrict__ Wlo,
    int Ksrc, int N, int Kpad, int krow0, const int* __restrict__ flags)
{
    __shared__ float tile[64][65];
    const int z = blockIdx.z;
    const int nb = blockIdx.x * 64;
    const int kb = blockIdx.y * 64;
    const int f32m = flags[0];
    const int lx = threadIdx.x & 63;
    const size_t dsto = (size_t)z * N * Kpad;
    const int kro = krow0 + z * 512;

    for (int rr = threadIdx.x >> 6; rr < 64; rr += 4) {
        const int k = kb + rr;
        const int n = nb + lx;
        float v = 0.f;
        if (k < Ksrc && n < N) v = ldf(W, (size_t)(kro + k) * N + n, f32m);
        tile[rr][lx] = v;
    }
    __syncthreads();
    for (int rr = threadIdx.x >> 6; rr < 64; rr += 4) {
        const int n = nb + rr;
        const int k = kb + lx;
        if (n < N && k < Kpad) {
            __bf16 hi, lo; split2(tile[lx][rr], hi, lo);
            Whi[dsto + (size_t)n * Kpad + k] = hi;
            Wlo[dsto + (size_t)n * Kpad + k] = lo;
        }
    }
}

// A_init[e,0:160] = [x[row[e],0:133], ea[e,0:14], 0] -> hi/lo; one thread per 8-f chunk
__global__ void build_Ainit_split8(const void* __restrict__ x, const void* __restrict__ ea,
                                   const int* __restrict__ row, __bf16* __restrict__ Ah,
                                   __bf16* __restrict__ Al, const int* __restrict__ flags)
{
    long idx = (long)blockIdx.x * 256 + threadIdx.x;
    if (idx >= (long)E_EDGES * 20) return;
    const int e = (int)(idx / 20), c = (int)(idx % 20);
    const int f0 = c * 8;
    const int f32m = flags[0];
    const int r = row[e];
    bf16x8 oh, ol;
    #pragma unroll
    for (int j = 0; j < 8; ++j) {
        const int f = f0 + j;
        float v = 0.f;
        if (f < 133)      v = ldf(x, (size_t)r * 133 + f, f32m);
        else if (f < 147) v = ldf(ea, (size_t)e * 14 + (f - 133), f32m);
        __bf16 hi, lo; split2(v, hi, lo);
        oh[j] = hi; ol[j] = lo;
    }
    *(bf16x8*)(Ah + (size_t)e * 160 + f0) = oh;
    *(bf16x8*)(Al + (size_t)e * 160 + f0) = ol;
}

// A_e2n[n,0:672] = [x[n,0:133], s_f32[n,0:512], 0] -> hi/lo; one thread per 8-f chunk
__global__ void build_Ae2n_split8(const void* __restrict__ x, const float* __restrict__ s,
                                  __bf16* __restrict__ Ah, __bf16* __restrict__ Al,
                                  const int* __restrict__ flags)
{
    long idx = (long)blockIdx.x * 256 + threadIdx.x;
    if (idx >= (long)N_NODES * 84) return;
    const int n = (int)(idx / 84), c = (int)(idx % 84);
    const int f0 = c * 8;
    const int f32m = flags[0];
    bf16x8 oh, ol;
    #pragma unroll
    for (int j = 0; j < 8; ++j) {
        const int f = f0 + j;
        float v = 0.f;
        if (f < 133)      v = ldf(x, (size_t)n * 133 + f, f32m);
        else if (f < 645) v = s[(size_t)n * HID + (f - 133)];
        __bf16 hi, lo; split2(v, hi, lo);
        oh[j] = hi; ol[j] = lo;
    }
    *(bf16x8*)(Ah + (size_t)n * 672 + f0) = oh;
    *(bf16x8*)(Al + (size_t)n * 672 + f0) = ol;
}

// Wide split-precision GEMM: C[M,512] = relu(A @ BT^T + bias), 3-term MFMA.
// r12: per-wave LDS-staged epilogue -> 64B-granule row-major writes
// (was 2B scattered stores: 2.4x HBM write amplification, WRITE 246MB vs 102).
__global__ __launch_bounds__(1024) void gemm3w(
    const __bf16* __restrict__ Ah, const __bf16* __restrict__ Al,
    const __bf16* __restrict__ Bh, const __bf16* __restrict__ Bl,
    const void* __restrict__ bias,
    void* __restrict__ C, int out_f32, int M, int K, const int* __restrict__ flags)
{
    __shared__ __bf16 lAh[128 * 32];
    __shared__ __bf16 lAl[128 * 32];
    __shared__ __bf16 lBh[512 * 32];
    __shared__ char   lEpi[16 * 4864];   // per-wave epilogue staging (77.8KB)

    const int m0 = blockIdx.x * 128;
    const int tid = threadIdx.x;
    const int w = tid >> 6;
    const int lane = tid & 63;

    const int ac = tid & 511;
    int arow = m0 + (ac >> 2); if (arow >= M) arow = M - 1;
    const int akc = (ac & 3) << 3;
    const __bf16* Asrc = (tid < 512) ? Ah : Al;
    const size_t ag = (size_t)arow * K + akc;
    __bf16* aw = ((tid < 512) ? lAh : lAl) + (ac >> 2) * 32 + akc;

    const size_t bg0 = (size_t)(tid >> 2) * K + ((tid & 3) << 3);
    const size_t bg1 = (size_t)((tid + 1024) >> 2) * K + (((tid + 1024) & 3) << 3);
    __bf16* wB0 = lBh + (size_t)tid * 8;
    __bf16* wB1 = lBh + (size_t)(tid + 1024) * 8;

    const int mh = (w >> 3) * 64;
    const int nq = (w & 7) * 64;
    const int c16 = lane & 15;
    const int quad = lane >> 4;

    const __bf16* blp = Bl + (size_t)(nq + c16) * K + quad * 8;

    f32x4 acc[4][4] = {};

    for (int k0 = 0; k0 < K; k0 += 32) {
        gload_lds16(Asrc + ag + k0, aw);
        gload_lds16(Bh + bg0 + k0, wB0);
        gload_lds16(Bh + bg1 + k0, wB1);
        __syncthreads();

        bf16x8 bl[4];
        #pragma unroll
        for (int j = 0; j < 4; ++j)
            bl[j] = *(const bf16x8*)(blp + (size_t)(j * 16) * K + k0);

        bf16x8 ah[4], al[4];
        #pragma unroll
        for (int i = 0; i < 4; ++i) {
            ah[i] = *(const bf16x8*)(lAh + (mh + i * 16 + c16) * 32 + quad * 8);
            al[i] = *(const bf16x8*)(lAl + (mh + i * 16 + c16) * 32 + quad * 8);
        }
        #pragma unroll
        for (int j = 0; j < 4; ++j) {
            bf16x8 bh = *(const bf16x8*)(lBh + (nq + j * 16 + c16) * 32 + quad * 8);
            #pragma unroll
            for (int i = 0; i < 4; ++i) {
                acc[i][j] = __builtin_amdgcn_mfma_f32_16x16x32_bf16(ah[i], bh, acc[i][j], 0, 0, 0);
                acc[i][j] = __builtin_amdgcn_mfma_f32_16x16x32_bf16(al[i], bh, acc[i][j], 0, 0, 0);
                acc[i][j] = __builtin_amdgcn_mfma_f32_16x16x32_bf16(ah[i], bl[j], acc[i][j], 0, 0, 0);
            }
        }
        __syncthreads();
    }

    const int f32 = flags[0];
    if (out_f32) {
        float* epf = (float*)(lEpi + (size_t)w * 4864);   // [64][19] f32
        float* Cf = (float*)C;
        #pragma unroll
        for (int j = 0; j < 4; ++j) {
            const float bv = ldf(bias, nq + j * 16 + c16, f32);
            #pragma unroll
            for (int i = 0; i < 4; ++i)
                #pragma unroll
                for (int rr = 0; rr < 4; ++rr) {
                    float v = acc[i][j][rr] + bv;
                    epf[(i * 16 + quad * 4 + rr) * 19 + c16] = v > 0.f ? v : 0.f;
                }
            #pragma unroll
            for (int it = 0; it < 4; ++it) {
                const int c = it * 64 + lane;
                const int rowL = c >> 2, qc = c & 3;
                f32x4 v = *(const f32x4*)&epf[rowL * 19 + qc * 4];
                const int grow = m0 + mh + rowL;
                if (grow < M)
                    *(f32x4*)(Cf + (size_t)grow * HID + nq + j * 16 + qc * 4) = v;
            }
        }
    } else {
        __bf16* ep = (__bf16*)(lEpi + (size_t)w * 4864);  // [64][34] bf16
        __bf16* Cb = (__bf16*)C;
        #pragma unroll
        for (int jp = 0; jp < 2; ++jp) {
            #pragma unroll
            for (int j2 = 0; j2 < 2; ++j2) {
                const int j = jp * 2 + j2;
                const float bv = ldf(bias, nq + j * 16 + c16, f32);
                #pragma unroll
                for (int i = 0; i < 4; ++i)
                    #pragma unroll
                    for (int rr = 0; rr < 4; ++rr) {
                        float v = acc[i][j][rr] + bv;
                        ep[(i * 16 + quad * 4 + rr) * 34 + j2 * 16 + c16] = rtne(v > 0.f ? v : 0.f);
                    }
            }
            #pragma unroll
            for (int it = 0; it < 4; ++it) {
                const int c = it * 64 + lane;
                const int rowL = c >> 2, qc = c & 3;
                bf16x8 v = *(const bf16x8*)&ep[rowL * 34 + qc * 8];
                const int grow = m0 + mh + rowL;
                if (grow < M)
                    *(bf16x8*)(Cb + (size_t)grow * HID + nq + jp * 32 + qc * 8) = v;
            }
        }
    }
}

// Streaming GEMM g = h @ Wh^T, 1-TERM, ROW-MAJOR [E][512]. 512-thr /
// BM=128 / BN=256 col-split: 2 blocks/CU. REQUIRES src != dst (layer 0).
// r12: LDS-staged epilogue (64B-granule writes).
__global__ __launch_bounds__(512, 4) void gemmg512(
    const __bf16* __restrict__ hsrc, const __bf16* __restrict__ Bh,
    __bf16* __restrict__ g, int M)
{
    __shared__ __bf16 lA[128 * 32];        //  8KB
    __shared__ __bf16 lB[256 * 32];        // 16KB
    __shared__ __bf16 lEp[8 * 64 * 34];    // 34.8KB (total 59.4KB -> 2 blocks OK)

    const int m0 = blockIdx.x * 128;
    const int nc = blockIdx.y * 256;
    const int tid = threadIdx.x;
    const int w = tid >> 6;
    const int lane = tid & 63;

    int arow = m0 + (tid >> 2); if (arow >= M) arow = M - 1;
    const size_t ag = (size_t)arow * HID + ((tid & 3) << 3);

    const int c0 = tid, c1 = tid + 512;
    const size_t bg0 = (size_t)(nc + (c0 >> 2)) * HID + ((c0 & 3) << 3);
    const size_t bg1 = (size_t)(nc + (c1 >> 2)) * HID + ((c1 & 3) << 3);

    const int mh = (w >> 2) * 64;
    const int nqw = (w & 3) * 64;
    const int c16 = lane & 15;
    const int quad = lane >> 4;

    f32x4 acc[4][4] = {};

    for (int k0 = 0; k0 < HID; k0 += 32) {
        gload_lds16(hsrc + ag + k0, &lA[tid * 8]);
        gload_lds16(Bh + bg0 + k0, &lB[c0 * 8]);
        gload_lds16(Bh + bg1 + k0, &lB[c1 * 8]);
        __syncthreads();

        bf16x8 ah[4];
        #pragma unroll
        for (int i = 0; i < 4; ++i)
            ah[i] = *(const bf16x8*)&lA[(mh + i * 16 + c16) * 32 + quad * 8];

        #pragma unroll
        for (int j = 0; j < 4; ++j) {
            bf16x8 bh = *(const bf16x8*)&lB[(nqw + j * 16 + c16) * 32 + quad * 8];
            #pragma unroll
            for (int i = 0; i < 4; ++i)
                acc[i][j] = __builtin_amdgcn_mfma_f32_16x16x32_bf16(ah[i], bh, acc[i][j], 0, 0, 0);
        }
        __syncthreads();
    }

    __bf16* ep = lEp + (size_t)w * (64 * 34);
    #pragma unroll
    for (int jp = 0; jp < 2; ++jp) {
        #pragma unroll
        for (int j2 = 0; j2 < 2; ++j2) {
            const int j = jp * 2 + j2;
            #pragma unroll
            for (int i = 0; i < 4; ++i)
                #pragma unroll
                for (int rr = 0; rr < 4; ++rr)
                    ep[(i * 16 + quad * 4 + rr) * 34 + j2 * 16 + c16] = rtne(acc[i][j][rr]);
        }
        #pragma unroll
        for (int it = 0; it < 4; ++it) {
            const int c = it * 64 + lane;
            const int rowL = c >> 2, qc = c & 3;
            bf16x8 v = *(const bf16x8*)&ep[rowL * 34 + qc * 8];
            const int grow = m0 + mh + rowL;
            if (grow < M)
                *(bf16x8*)(g + (size_t)grow * HID + nc + nqw + jp * 32 + qc * 8) = v;
        }
    }
}

// In-place-safe conv GEMM, 1-TERM, ROW-MAJOR. 1024 thr / BM=128 / BN=512,
// BK=32, single-buffer 2-barrier. Block owns all cols of its rows ->
// src == dst race-free. r12: LDS-staged epilogue.
__global__ __launch_bounds__(1024) void gemmg1024(
    const __bf16* __restrict__ hsrc, const __bf16* __restrict__ Bh,
    __bf16* __restrict__ g, int M)
{
    __shared__ __bf16 lA[128 * 32];        //  8KB
    __shared__ __bf16 lB[512 * 32];        // 32KB
    __shared__ __bf16 lEp[16 * 64 * 34];   // 69.6KB

    const int m0 = blockIdx.x * 128;
    const int tid = threadIdx.x;
    const int w = tid >> 6;
    const int lane = tid & 63;

    const bool astage = (tid < 512);
    const int ac = tid & 511;
    int arow = m0 + (ac >> 2); if (arow >= M) arow = M - 1;
    const size_t ag = (size_t)arow * HID + ((ac & 3) << 3);

    const size_t bg0 = (size_t)(tid >> 2) * HID + ((tid & 3) << 3);
    const size_t bg1 = (size_t)((tid + 1024) >> 2) * HID + (((tid + 1024) & 3) << 3);

    const int mh = (w >> 3) * 64;
    const int nq = (w & 7) * 64;
    const int c16 = lane & 15;
    const int quad = lane >> 4;

    f32x4 acc[4][4] = {};

    for (int k0 = 0; k0 < HID; k0 += 32) {
        if (astage)
            gload_lds16(hsrc + ag + k0, &lA[ac * 8]);
        gload_lds16(Bh + bg0 + k0, &lB[tid * 8]);
        gload_lds16(Bh + bg1 + k0, &lB[(tid + 1024) * 8]);
        __syncthreads();

        bf16x8 ah[4];
        #pragma unroll
        for (int i = 0; i < 4; ++i)
            ah[i] = *(const bf16x8*)&lA[(mh + i * 16 + c16) * 32 + quad * 8];

        #pragma unroll
        for (int j = 0; j < 4; ++j) {
            bf16x8 bh = *(const bf16x8*)&lB[(nq + j * 16 + c16) * 32 + quad * 8];
            #pragma unroll
            for (int i = 0; i < 4; ++i)
                acc[i][j] = __builtin_amdgcn_mfma_f32_16x16x32_bf16(ah[i], bh, acc[i][j], 0, 0, 0);
        }
        __syncthreads();
    }

    __bf16* ep = lEp + (size_t)w * (64 * 34);
    #pragma unroll
    for (int jp = 0; jp < 2; ++jp) {
        #pragma unroll
        for (int j2 = 0; j2 < 2; ++j2) {
            const int j = jp * 2 + j2;
            #pragma unroll
            for (int i = 0; i < 4; ++i)
                #pragma unroll
                for (int rr = 0; rr < 4; ++rr)
                    ep[(i * 16 + quad * 4 + rr) * 34 + j2 * 16 + c16] = rtne(acc[i][j][rr]);
        }
        #pragma unroll
        for (int it = 0; it < 4; ++it) {
            const int c = it * 64 + lane;
            const int rowL = c >> 2, qc = c & 3;
            bf16x8 v = *(const bf16x8*)&ep[rowL * 34 + qc * 8];
            const int grow = m0 + mh + rowL;
            if (grow < M)
                *(bf16x8*)(g + (size_t)grow * HID + nq + jp * 32 + qc * 8) = v;
        }
    }
}

// h[e] = relu(gs[row[e]] - g[e^1] + b + h0[e]); ROW-MAJOR. One thread per
// (edge-pair, 8-col chunk); a wave = one pair -> contiguous 1KB wave reads.
__global__ __launch_bounds__(256) void combine_msg(
    const __bf16* __restrict__ g, const __bf16* __restrict__ gs,
    const int* __restrict__ row, const void* __restrict__ bias, int bias_off,
    const __bf16* __restrict__ h0, __bf16* __restrict__ hdst,
    const int* __restrict__ flags)
{
    long idx = (long)blockIdx.x * 256 + threadIdx.x;
    if (idx >= (long)(E_EDGES / 2) * 64) return;
    const int p = (int)(idx >> 6);
    const int k = (int)(idx & 63) * 8;
    const int e0 = 2 * p, e1 = 2 * p + 1;
    const int u0 = row[e0], u1 = row[e1];

    bf16x8 g0 = *(const bf16x8*)(g + (size_t)e0 * HID + k);
    bf16x8 g1 = *(const bf16x8*)(g + (size_t)e1 * HID + k);
    bf16x8 r0 = *(const bf16x8*)(h0 + (size_t)e0 * HID + k);
    bf16x8 r1 = *(const bf16x8*)(h0 + (size_t)e1 * HID + k);
    bf16x8 s0 = *(const bf16x8*)(gs + (size_t)u0 * HID + k);
    bf16x8 s1 = *(const bf16x8*)(gs + (size_t)u1 * HID + k);

    const int f32 = flags[0];
    bf16x8 o0, o1;
    #pragma unroll
    for (int j = 0; j < 8; ++j) {
        const float bv = ldf(bias, bias_off + k + j, f32);
        float v0 = (float)s0[j] - (float)g1[j] + bv + (float)r0[j];
        float v1 = (float)s1[j] - (float)g0[j] + bv + (float)r1[j];
        o0[j] = rtne(v0 > 0.f ? v0 : 0.f);
        o1[j] = rtne(v1 > 0.f ? v1 : 0.f);
    }
    *(bf16x8*)(hdst + (size_t)e0 * HID + k) = o0;
    *(bf16x8*)(hdst + (size_t)e1 * HID + k) = o1;
}

__global__ void bucket_build(const int* __restrict__ col, int* __restrict__ counts,
                             int* __restrict__ buckets, int E)
{
    int e = blockIdx.x * 256 + threadIdx.x;
    if (e >= E) return;
    int c = col[e];
    int p = atomicAdd(&counts[c], 1);
    if (p < CAP) buckets[(size_t)c * CAP + p] = e;
}

// Vectorized segsum, ROW-MAJOR input [E][512]: one thread per (node, 8-col
// chunk); a wave (= one node) reads a contiguous 1KB line per bucket edge.
__global__ __launch_bounds__(256) void segsum8(
    const __bf16* __restrict__ h, const int* __restrict__ counts,
    const int* __restrict__ buckets, __bf16* __restrict__ abf,
    float* __restrict__ af32)
{
    const int nid = blockIdx.x * 4 + (threadIdx.x >> 6);
    const int fc = threadIdx.x & 63;
    if (nid >= N_NODES) return;
    const int k = fc * 8;
    int cnt = counts[nid]; if (cnt > CAP) cnt = CAP;
    const int* bl = buckets + (size_t)nid * CAP;
    float s[8] = {0.f, 0.f, 0.f, 0.f, 0.f, 0.f, 0.f, 0.f};
    for (int i = 0; i < cnt; ++i) {
        const int e = bl[i];
        bf16x8 v = *(const bf16x8*)(h + (size_t)e * HID + k);
        #pragma unroll
        for (int j = 0; j < 8; ++j) s[j] += (float)v[j];
    }
    if (af32) {
        f32x4* out = (f32x4*)(af32 + (size_t)nid * HID + k);
        out[0] = f32x4{s[0], s[1], s[2], s[3]};
        out[1] = f32x4{s[4], s[5], s[6], s[7]};
    } else {
        bf16x8 o;
        #pragma unroll
        for (int j = 0; j < 8; ++j) o[j] = rtne(s[j]);
        *(bf16x8*)(abf + (size_t)nid * HID + k) = o;
    }
}

__global__ void graph_starts(const int* __restrict__ batch, int* __restrict__ gstart, int N, int G)
{
    int n = blockIdx.x * 256 + threadIdx.x;
    if (n >= N) return;
    int b = batch[n];
    if (n == 0) {
        for (int g = 0; g <= b; ++g) gstart[g] = 0;
    } else {
        int pb = batch[n - 1];
        for (int g = pb + 1; g <= b; ++g) gstart[g] = n;
    }
    if (n == N - 1) {
        for (int g = b + 1; g <= G; ++g) gstart[g] = N;
    }
}

__global__ void pool_nodes(const float* __restrict__ hn, const int* __restrict__ gstart,
                           float* __restrict__ Apool)
{
    int g = blockIdx.x;
    int s = gstart[g], e = gstart[g + 1];
    for (int f = threadIdx.x; f < HID; f += 256) {
        float acc = 0.f;
        for (int n = s; n < e; ++n) acc += hn[(size_t)n * HID + f];
        Apool[(size_t)g * HID + f] = acc;
    }
}

// fused ffn: per block 8 graphs; t = relu(Apool@W1+b1); out = t@W2 + b2 (all f32)
__global__ __launch_bounds__(256) void ffn_fused(
    const float* __restrict__ Apool, const void* __restrict__ W1,
    const void* __restrict__ b1, const void* __restrict__ W2,
    const void* __restrict__ b2v, void* __restrict__ outv,
    const int* __restrict__ flags)
{
    __shared__ float sA[8][512];
    __shared__ float t[8][512];
    __shared__ float sW2[512];
    __shared__ float red[4];
    const int tid = threadIdx.x;
    const int g0 = blockIdx.x * 8;
    const int f32 = flags[0];

    for (int i = tid; i < 4096; i += 256)
        sA[i >> 9][i & 511] = Apool[(size_t)g0 * 512 + i];
    for (int n = tid; n < 512; n += 256)
        sW2[n] = ldf(W2, n, f32);
    __syncthreads();

    {
        float acc0[8], acc1[8];
        const float bb0 = ldf(b1, tid, f32);
        const float bb1 = ldf(b1, tid + 256, f32);
        #pragma unroll
        for (int gi = 0; gi < 8; ++gi) { acc0[gi] = bb0; acc1[gi] = bb1; }
        if (f32) {
            const float* Wf = (const float*)W1;
            for (int k = 0; k < 512; ++k) {
                float w0 = Wf[(size_t)k * 512 + tid];
                float w1 = Wf[(size_t)k * 512 + tid + 256];
                #pragma unroll
                for (int gi = 0; gi < 8; ++gi) {
                    float a = sA[gi][k];
                    acc0[gi] += a * w0;
                    acc1[gi] += a * w1;
                }
            }
        } else {
            const __bf16* Wb = (const __bf16*)W1;
            for (int k = 0; k < 512; ++k) {
                float w0 = (float)Wb[(size_t)k * 512 + tid];
                float w1 = (float)Wb[(size_t)k * 512 + tid + 256];
                #pragma unroll
                for (int gi = 0; gi < 8; ++gi) {
                    float a = sA[gi][k];
                    acc0[gi] += a * w0;
                    acc1[gi] += a * w1;
                }
            }
        }
        #pragma unroll
        for (int gi = 0; gi < 8; ++gi) {
            t[gi][tid]       = acc0[gi] > 0.f ? acc0[gi] : 0.f;
            t[gi][tid + 256] = acc1[gi] > 0.f ? acc1[gi] : 0.f;
        }
    }
    __syncthreads();

    const int lane = tid & 63;
    const int w = tid >> 6;
    const float b2 = ldf(b2v, 0, f32);
    for (int gi = 0; gi < 8; ++gi) {
        float p = t[gi][tid] * sW2[tid] + t[gi][tid + 256] * sW2[tid + 256];
        for (int o = 32; o; o >>= 1) p += __shfl_down(p, o, 64);
        if (lane == 0) red[w] = p;
        __syncthreads();
        if (tid == 0) {
            float r = red[0] + red[1] + red[2] + red[3] + b2;
            if (f32) ((float*)outv)[g0 + gi] = r;
            else     ((__bf16*)outv)[g0 + gi] = rtne(r);
        }
        __syncthreads();
    }
}

extern "C" void kernel_launch(void* const* d_in, const int* in_sizes, int n_in,
                              void* d_out, int out_size, void* d_ws, size_t ws_size,
                              hipStream_t stream)
{
    const int E = E_EDGES, NN = N_NODES, G = N_GRAPHS;

    char* wsp = (char*)d_ws;
    size_t off = 0;
    auto carve = [&](size_t bytes) -> void* {
        void* p = wsp + off;
        off += (bytes + 511) & ~(size_t)511;
        return p;
    };

    // r6 carve order (r8's reordering regressed via placement effects).
    __bf16* h0    = (__bf16*)carve((size_t)E * HID * 2);   // ROW-MAJOR [E][512]
    __bf16* h     = (__bf16*)carve((size_t)E * HID * 2);   // ROW-MAJOR layer state
    __bf16* abuf  = (__bf16*)carve((size_t)NN * HID * 2);  // row-major; gs each layer
    float*  Apool = (float*) carve((size_t)G * HID * 4);
    __bf16* WTih  = (__bf16*)carve((size_t)512 * 160 * 2);
    __bf16* WTil  = (__bf16*)carve((size_t)512 * 160 * 2);
    __bf16* WTch  = (__bf16*)carve((size_t)4 * 512 * 512 * 2);
    __bf16* WTcl  = (__bf16*)carve((size_t)4 * 512 * 512 * 2);
    __bf16* WTqh  = (__bf16*)carve((size_t)512 * 672 * 2);
    __bf16* WTql  = (__bf16*)carve((size_t)512 * 672 * 2);
    int*    ei32  = (int*)   carve((size_t)2 * E * 4);
    int*    b32   = (int*)   carve((size_t)NN * 4);
    int*    counts= (int*)   carve((size_t)NN * 4);
    int*    bucket= (int*)   carve((size_t)NN * CAP * 4);
    int*    gstart= (int*)   carve((size_t)(G + 1) * 4);
    int*    flags = (int*)   carve(2 * 4);

    // aliases into provably-dead regions
    __bf16* Aih = h;                              // E*160 bf16; h dead until layer-0 output
    __bf16* Ail = h + (size_t)E * 160;
    __bf16* Aqh = h;                              // h dead after final segsum
    __bf16* Aql = h + (size_t)NN * 672;
    float*  hn   = (float*)h0;                    // NN*512 f32; h0 dead after layer-3 combine
    float*  sfin = (float*)((char*)h0 + (size_t)NN * HID * 4);  // NN*512 f32 (row-major)

    if (off > ws_size) {  // clean fail instead of faulting
        hipMemsetAsync(d_out, 0, (size_t)out_size * 4, stream);
        return;
    }

    auto cdiv = [](long a, long b) { return (int)((a + b - 1) / b); };

    probe_dtypes<<<1, 256, 0, stream>>>((const unsigned*)d_in[0], (const unsigned*)d_in[1], flags);
    to_int32<<<cdiv((long)2 * E, 256), 256, 0, stream>>>(d_in[1], ei32, (long)2 * E, flags);
    to_int32<<<cdiv(NN, 256), 256, 0, stream>>>(d_in[3], b32, NN, flags);

    const int* row = ei32;
    const int* col = ei32 + E;

    hipMemsetAsync(counts, 0, (size_t)NN * 4, stream);

    split_transpose_t<<<dim3(8, 3, 1), 256, 0, stream>>>(d_in[4], WTih, WTil, 147, 512, 160, 0, flags);
    split_transpose_t<<<dim3(8, 8, 4), 256, 0, stream>>>(d_in[6], WTch, WTcl, 512, 512, 512, 0, flags);
    split_transpose_t<<<dim3(8, 11, 1), 256, 0, stream>>>(d_in[8], WTqh, WTql, 645, 512, 672, 0, flags);

    bucket_build<<<cdiv(E, 256), 256, 0, stream>>>(col, counts, bucket, E);

    // edge init: h0 = relu([x[row], ea] @ W_ei + b_ei) -> ROW-MAJOR (3-term)
    build_Ainit_split8<<<cdiv((long)E * 20, 256), 256, 0, stream>>>(d_in[0], d_in[2], row, Aih, Ail, flags);
    gemm3w<<<cdiv(E, 128), 1024, 0, stream>>>(Aih, Ail, WTih, WTil, d_in[5], h0, 0, E, 160, flags);

    // DMPNN layers: g = h@W (1-term); gs = segsum(g); h = relu(gs[row] - g[rev] + b + h0)
    const long ncomb = (long)(E / 2) * 64;
    for (int l = 0; l < 4; ++l) {
        const __bf16* Wh = WTch + (size_t)l * 512 * 512;
        if (l == 0)   // h0 -> h: src != dst, col-split 2-blocks/CU
            gemmg512<<<dim3(cdiv(E, 128), 2), 512, 0, stream>>>(h0, Wh, h, E);
        else          // h -> h in-place (block owns all cols of its rows)
            gemmg1024<<<cdiv(E, 128), 1024, 0, stream>>>(h, Wh, h, E);
        segsum8<<<cdiv(NN, 4), 256, 0, stream>>>(h, counts, bucket, abuf, nullptr);
        combine_msg<<<cdiv(ncomb, 256), 256, 0, stream>>>(h, abuf, row, d_in[7], l * 512, h0, h, flags);
    }

    // final aggregation (f32, row-major out) + e2n (wide 3-term GEMM, f32 row-major out)
    segsum8<<<cdiv(NN, 4), 256, 0, stream>>>(h, counts, bucket, nullptr, sfin);
    build_Ae2n_split8<<<cdiv((long)NN * 84, 256), 256, 0, stream>>>(d_in[0], sfin, Aqh, Aql, flags);
    gemm3w<<<cdiv(NN, 128), 1024, 0, stream>>>(Aqh, Aql, WTqh, WTql, d_in[9], hn, 1, NN, 672, flags);

    // pool + fused ffn (all f32)
    graph_starts<<<cdiv(NN, 256), 256, 0, stream>>>(b32, gstart, NN, G);
    pool_nodes<<<G, 256, 0, stream>>>(hn, gstart, Apool);
    ffn_fused<<<G / 8, 256, 0, stream>>>(Apool, d_in[10], d_in[11], d_in[12], d_in[13], d_out, flags);
}

// Round 13
// 1267.750 us; speedup vs baseline: 1.4442x; 1.0333x over previous
//
#include <hip/hip_runtime.h>

typedef __bf16 bf16x8 __attribute__((ext_vector_type(8)));
typedef float  f32x4  __attribute__((ext_vector_type(4)));

#define E_EDGES 100000
#define N_NODES 25000
#define N_GRAPHS 2048
#define HID 512
#define CAP 32

__device__ __forceinline__ void gload_lds16(const void* g, void* l) {
    __builtin_amdgcn_global_load_lds(
        (const __attribute__((address_space(1))) void*)g,
        (__attribute__((address_space(3))) void*)l, 16, 0, 0);
}

__device__ __forceinline__ __bf16 rtne(float x) {
    union { unsigned short s; __bf16 b; } u;
    unsigned v = __float_as_uint(x);
    u.s = (unsigned short)((v + 0x7FFF + ((v >> 16) & 1)) >> 16);
    return u.b;
}

__device__ __forceinline__ void split2(float x, __bf16& hi, __bf16& lo) {
    hi = rtne(x);
    lo = rtne(x - (float)hi);
}

__device__ __forceinline__ float ldf(const void* p, long i, int f32) {
    return f32 ? ((const float*)p)[i] : (float)(((const __bf16*)p)[i]);
}

// flags[0]=1 if float inputs are f32 (else bf16); flags[1]=1 if int inputs are i64
__global__ void probe_dtypes(const unsigned* __restrict__ xr, const unsigned* __restrict__ eir,
                             int* __restrict__ flags)
{
    __shared__ int cfp, ci;
    if (threadIdx.x == 0) { cfp = 0; ci = 0; }
    __syncthreads();
    int lc = 0;
    for (int i = threadIdx.x; i < 1024; i += 256) {
        unsigned elo = (xr[i] >> 7) & 0xFFu;
        if (elo > 140u) lc++;
    }
    atomicAdd(&cfp, lc);
    int ln = 0;
    for (int i = threadIdx.x; i < 512; i += 256) {
        if (eir[2 * i + 1] != 0u) ln++;
    }
    atomicAdd(&ci, ln);
    __syncthreads();
    if (threadIdx.x == 0) {
        flags[0] = (cfp > 100) ? 1 : 0;
        flags[1] = (ci < 256) ? 1 : 0;
    }
}

__global__ void to_int32(const void* __restrict__ src, int* __restrict__ dst, long n,
                         const int* __restrict__ flags)
{
    long i = (long)blockIdx.x * 256 + threadIdx.x;
    if (i >= n) return;
    dst[i] = flags[1] ? (int)((const long long*)src)[i] : ((const int*)src)[i];
}

// Tiled transpose+split: WThi/WTlo[n,k] = split(W[krow0 + z*512 + k, n]), zero-pad to Kpad.
__global__ __launch_bounds__(256) void split_transpose_t(
    const void* __restrict__ W, __bf16* __restrict__ Whi, __bf16* __restrict__ Wlo,
    int Ksrc, int N, int Kpad, int krow0, const int* __restrict__ flags)
{
    __shared__ float tile[64][65];
    const int z = blockIdx.z;
    const int nb = blockIdx.x * 64;
    const int kb = blockIdx.y * 64;
    const int f32m = flags[0];
    const int lx = threadIdx.x & 63;
    const size_t dsto = (size_t)z * N * Kpad;
    const int kro = krow0 + z * 512;

    for (int rr = threadIdx.x >> 6; rr < 64; rr += 4) {
        const int k = kb + rr;
        const int n = nb + lx;
        float v = 0.f;
        if (k < Ksrc && n < N) v = ldf(W, (size_t)(kro + k) * N + n, f32m);
        tile[rr][lx] = v;
    }
    __syncthreads();
    for (int rr = threadIdx.x >> 6; rr < 64; rr += 4) {
        const int n = nb + rr;
        const int k = kb + lx;
        if (n < N && k < Kpad) {
            __bf16 hi, lo; split2(tile[lx][rr], hi, lo);
            Whi[dsto + (size_t)n * Kpad + k] = hi;
            Wlo[dsto + (size_t)n * Kpad + k] = lo;
        }
    }
}

// A_init[e,0:160] = [x[row[e],0:133], ea[e,0:14], 0] -> hi/lo; one thread per 8-f chunk
__global__ void build_Ainit_split8(const void* __restrict__ x, const void* __restrict__ ea,
                                   const int* __restrict__ row, __bf16* __restrict__ Ah,
                                   __bf16* __restrict__ Al, const int* __restrict__ flags)
{
    long idx = (long)blockIdx.x * 256 + threadIdx.x;
    if (idx >= (long)E_EDGES * 20) return;
    const int e = (int)(idx / 20), c = (int)(idx % 20);
    const int f0 = c * 8;
    const int f32m = flags[0];
    const int r = row[e];
    bf16x8 oh, ol;
    #pragma unroll
    for (int j = 0; j < 8; ++j) {
        const int f = f0 + j;
        float v = 0.f;
        if (f < 133)      v = ldf(x, (size_t)r * 133 + f, f32m);
        else if (f < 147) v = ldf(ea, (size_t)e * 14 + (f - 133), f32m);
        __bf16 hi, lo; split2(v, hi, lo);
        oh[j] = hi; ol[j] = lo;
    }
    *(bf16x8*)(Ah + (size_t)e * 160 + f0) = oh;
    *(bf16x8*)(Al + (size_t)e * 160 + f0) = ol;
}

// A_e2n[n,0:672] = [x[n,0:133], s_f32[n,0:512], 0] -> hi/lo; one thread per 8-f chunk
__global__ void build_Ae2n_split8(const void* __restrict__ x, const float* __restrict__ s,
                                  __bf16* __restrict__ Ah, __bf16* __restrict__ Al,
                                  const int* __restrict__ flags)
{
    long idx = (long)blockIdx.x * 256 + threadIdx.x;
    if (idx >= (long)N_NODES * 84) return;
    const int n = (int)(idx / 84), c = (int)(idx % 84);
    const int f0 = c * 8;
    const int f32m = flags[0];
    bf16x8 oh, ol;
    #pragma unroll
    for (int j = 0; j < 8; ++j) {
        const int f = f0 + j;
        float v = 0.f;
        if (f < 133)      v = ldf(x, (size_t)n * 133 + f, f32m);
        else if (f < 645) v = s[(size_t)n * HID + (f - 133)];
        __bf16 hi, lo; split2(v, hi, lo);
        oh[j] = hi; ol[j] = lo;
    }
    *(bf16x8*)(Ah + (size_t)n * 672 + f0) = oh;
    *(bf16x8*)(Al + (size_t)n * 672 + f0) = ol;
}

// Wide split-precision GEMM: C[M,512] = relu(A @ BT^T + bias), 3-term MFMA.
// LDS-staged epilogue (r12): 64B-granule row-major writes.
__global__ __launch_bounds__(1024) void gemm3w(
    const __bf16* __restrict__ Ah, const __bf16* __restrict__ Al,
    const __bf16* __restrict__ Bh, const __bf16* __restrict__ Bl,
    const void* __restrict__ bias,
    void* __restrict__ C, int out_f32, int M, int K, const int* __restrict__ flags)
{
    __shared__ __bf16 lAh[128 * 32];
    __shared__ __bf16 lAl[128 * 32];
    __shared__ __bf16 lBh[512 * 32];
    __shared__ char   lEpi[16 * 4864];   // per-wave epilogue staging (77.8KB)

    const int m0 = blockIdx.x * 128;
    const int tid = threadIdx.x;
    const int w = tid >> 6;
    const int lane = tid & 63;

    const int ac = tid & 511;
    int arow = m0 + (ac >> 2); if (arow >= M) arow = M - 1;
    const int akc = (ac & 3) << 3;
    const __bf16* Asrc = (tid < 512) ? Ah : Al;
    const size_t ag = (size_t)arow * K + akc;
    __bf16* aw = ((tid < 512) ? lAh : lAl) + (ac >> 2) * 32 + akc;

    const size_t bg0 = (size_t)(tid >> 2) * K + ((tid & 3) << 3);
    const size_t bg1 = (size_t)((tid + 1024) >> 2) * K + (((tid + 1024) & 3) << 3);
    __bf16* wB0 = lBh + (size_t)tid * 8;
    __bf16* wB1 = lBh + (size_t)(tid + 1024) * 8;

    const int mh = (w >> 3) * 64;
    const int nq = (w & 7) * 64;
    const int c16 = lane & 15;
    const int quad = lane >> 4;

    const __bf16* blp = Bl + (size_t)(nq + c16) * K + quad * 8;

    f32x4 acc[4][4] = {};

    for (int k0 = 0; k0 < K; k0 += 32) {
        gload_lds16(Asrc + ag + k0, aw);
        gload_lds16(Bh + bg0 + k0, wB0);
        gload_lds16(Bh + bg1 + k0, wB1);
        __syncthreads();

        bf16x8 bl[4];
        #pragma unroll
        for (int j = 0; j < 4; ++j)
            bl[j] = *(const bf16x8*)(blp + (size_t)(j * 16) * K + k0);

        bf16x8 ah[4], al[4];
        #pragma unroll
        for (int i = 0; i < 4; ++i) {
            ah[i] = *(const bf16x8*)(lAh + (mh + i * 16 + c16) * 32 + quad * 8);
            al[i] = *(const bf16x8*)(lAl + (mh + i * 16 + c16) * 32 + quad * 8);
        }
        #pragma unroll
        for (int j = 0; j < 4; ++j) {
            bf16x8 bh = *(const bf16x8*)(lBh + (nq + j * 16 + c16) * 32 + quad * 8);
            #pragma unroll
            for (int i = 0; i < 4; ++i) {
                acc[i][j] = __builtin_amdgcn_mfma_f32_16x16x32_bf16(ah[i], bh, acc[i][j], 0, 0, 0);
                acc[i][j] = __builtin_amdgcn_mfma_f32_16x16x32_bf16(al[i], bh, acc[i][j], 0, 0, 0);
                acc[i][j] = __builtin_amdgcn_mfma_f32_16x16x32_bf16(ah[i], bl[j], acc[i][j], 0, 0, 0);
            }
        }
        __syncthreads();
    }

    const int f32 = flags[0];
    if (out_f32) {
        float* epf = (float*)(lEpi + (size_t)w * 4864);   // [64][19] f32
        float* Cf = (float*)C;
        #pragma unroll
        for (int j = 0; j < 4; ++j) {
            const float bv = ldf(bias, nq + j * 16 + c16, f32);
            #pragma unroll
            for (int i = 0; i < 4; ++i)
                #pragma unroll
                for (int rr = 0; rr < 4; ++rr) {
                    float v = acc[i][j][rr] + bv;
                    epf[(i * 16 + quad * 4 + rr) * 19 + c16] = v > 0.f ? v : 0.f;
                }
            #pragma unroll
            for (int it = 0; it < 4; ++it) {
                const int c = it * 64 + lane;
                const int rowL = c >> 2, qc = c & 3;
                f32x4 v = *(const f32x4*)&epf[rowL * 19 + qc * 4];
                const int grow = m0 + mh + rowL;
                if (grow < M)
                    *(f32x4*)(Cf + (size_t)grow * HID + nq + j * 16 + qc * 4) = v;
            }
        }
    } else {
        __bf16* ep = (__bf16*)(lEpi + (size_t)w * 4864);  // [64][34] bf16
        __bf16* Cb = (__bf16*)C;
        #pragma unroll
        for (int jp = 0; jp < 2; ++jp) {
            #pragma unroll
            for (int j2 = 0; j2 < 2; ++j2) {
                const int j = jp * 2 + j2;
                const float bv = ldf(bias, nq + j * 16 + c16, f32);
                #pragma unroll
                for (int i = 0; i < 4; ++i)
                    #pragma unroll
                    for (int rr = 0; rr < 4; ++rr) {
                        float v = acc[i][j][rr] + bv;
                        ep[(i * 16 + quad * 4 + rr) * 34 + j2 * 16 + c16] = rtne(v > 0.f ? v : 0.f);
                    }
            }
            #pragma unroll
            for (int it = 0; it < 4; ++it) {
                const int c = it * 64 + lane;
                const int rowL = c >> 2, qc = c & 3;
                bf16x8 v = *(const bf16x8*)&ep[rowL * 34 + qc * 8];
                const int grow = m0 + mh + rowL;
                if (grow < M)
                    *(bf16x8*)(Cb + (size_t)grow * HID + nq + jp * 32 + qc * 8) = v;
            }
        }
    }
}

// Streaming GEMM g = h @ Wh^T, 1-TERM, ROW-MAJOR. 512-thr / BM=128 / BN=256
// col-split: 2 blocks/CU. REQUIRES src rows != dst rows. Used for layer 0
// (h0 -> state) and, when the window fits, all conv layers (chunked).
// LDS-staged epilogue (64B-granule writes).
__global__ __launch_bounds__(512, 4) void gemmg512(
    const __bf16* __restrict__ hsrc, const __bf16* __restrict__ Bh,
    __bf16* __restrict__ g, int M)
{
    __shared__ __bf16 lA[128 * 32];        //  8KB
    __shared__ __bf16 lB[256 * 32];        // 16KB
    __shared__ __bf16 lEp[8 * 64 * 34];    // 34.8KB (total 59.4KB -> 2 blocks OK)

    const int m0 = blockIdx.x * 128;
    const int nc = blockIdx.y * 256;
    const int tid = threadIdx.x;
    const int w = tid >> 6;
    const int lane = tid & 63;

    int arow = m0 + (tid >> 2); if (arow >= M) arow = M - 1;
    const size_t ag = (size_t)arow * HID + ((tid & 3) << 3);

    const int c0 = tid, c1 = tid + 512;
    const size_t bg0 = (size_t)(nc + (c0 >> 2)) * HID + ((c0 & 3) << 3);
    const size_t bg1 = (size_t)(nc + (c1 >> 2)) * HID + ((c1 & 3) << 3);

    const int mh = (w >> 2) * 64;
    const int nqw = (w & 3) * 64;
    const int c16 = lane & 15;
    const int quad = lane >> 4;

    f32x4 acc[4][4] = {};

    for (int k0 = 0; k0 < HID; k0 += 32) {
        gload_lds16(hsrc + ag + k0, &lA[tid * 8]);
        gload_lds16(Bh + bg0 + k0, &lB[c0 * 8]);
        gload_lds16(Bh + bg1 + k0, &lB[c1 * 8]);
        __syncthreads();

        bf16x8 ah[4];
        #pragma unroll
        for (int i = 0; i < 4; ++i)
            ah[i] = *(const bf16x8*)&lA[(mh + i * 16 + c16) * 32 + quad * 8];

        #pragma unroll
        for (int j = 0; j < 4; ++j) {
            bf16x8 bh = *(const bf16x8*)&lB[(nqw + j * 16 + c16) * 32 + quad * 8];
            #pragma unroll
            for (int i = 0; i < 4; ++i)
                acc[i][j] = __builtin_amdgcn_mfma_f32_16x16x32_bf16(ah[i], bh, acc[i][j], 0, 0, 0);
        }
        __syncthreads();
    }

    __bf16* ep = lEp + (size_t)w * (64 * 34);
    #pragma unroll
    for (int jp = 0; jp < 2; ++jp) {
        #pragma unroll
        for (int j2 = 0; j2 < 2; ++j2) {
            const int j = jp * 2 + j2;
            #pragma unroll
            for (int i = 0; i < 4; ++i)
                #pragma unroll
                for (int rr = 0; rr < 4; ++rr)
                    ep[(i * 16 + quad * 4 + rr) * 34 + j2 * 16 + c16] = rtne(acc[i][j][rr]);
        }
        #pragma unroll
        for (int it = 0; it < 4; ++it) {
            const int c = it * 64 + lane;
            const int rowL = c >> 2, qc = c & 3;
            bf16x8 v = *(const bf16x8*)&ep[rowL * 34 + qc * 8];
            const int grow = m0 + mh + rowL;
            if (grow < M)
                *(bf16x8*)(g + (size_t)grow * HID + nc + nqw + jp * 32 + qc * 8) = v;
        }
    }
}

// In-place-safe conv GEMM fallback, 1-TERM, ROW-MAJOR (r11 form — direct
// stores; r12's LDS epilogue regressed this kernel 139->144). 1024 thr /
// BM=128 / BN=512, BK=32. Block owns all cols of its rows -> in-place OK.
__global__ __launch_bounds__(1024) void gemmg1024(
    const __bf16* __restrict__ hsrc, const __bf16* __restrict__ Bh,
    __bf16* __restrict__ g, int M)
{
    __shared__ __bf16 lA[128 * 32];   //  8KB
    __shared__ __bf16 lB[512 * 32];   // 32KB

    const int m0 = blockIdx.x * 128;
    const int tid = threadIdx.x;
    const int w = tid >> 6;
    const int lane = tid & 63;

    const bool astage = (tid < 512);
    const int ac = tid & 511;
    int arow = m0 + (ac >> 2); if (arow >= M) arow = M - 1;
    const size_t ag = (size_t)arow * HID + ((ac & 3) << 3);

    const size_t bg0 = (size_t)(tid >> 2) * HID + ((tid & 3) << 3);
    const size_t bg1 = (size_t)((tid + 1024) >> 2) * HID + (((tid + 1024) & 3) << 3);

    const int mh = (w >> 3) * 64;
    const int nq = (w & 7) * 64;
    const int c16 = lane & 15;
    const int quad = lane >> 4;

    f32x4 acc[4][4] = {};

    for (int k0 = 0; k0 < HID; k0 += 32) {
        if (astage)
            gload_lds16(hsrc + ag + k0, &lA[ac * 8]);
        gload_lds16(Bh + bg0 + k0, &lB[tid * 8]);
        gload_lds16(Bh + bg1 + k0, &lB[(tid + 1024) * 8]);
        __syncthreads();

        bf16x8 ah[4];
        #pragma unroll
        for (int i = 0; i < 4; ++i)
            ah[i] = *(const bf16x8*)&lA[(mh + i * 16 + c16) * 32 + quad * 8];

        #pragma unroll
        for (int j = 0; j < 4; ++j) {
            bf16x8 bh = *(const bf16x8*)&lB[(nq + j * 16 + c16) * 32 + quad * 8];
            #pragma unroll
            for (int i = 0; i < 4; ++i)
                acc[i][j] = __builtin_amdgcn_mfma_f32_16x16x32_bf16(ah[i], bh, acc[i][j], 0, 0, 0);
        }
        __syncthreads();
    }

    #pragma unroll
    for (int j = 0; j < 4; ++j) {
        const int gcol = nq + j * 16 + c16;
        #pragma unroll
        for (int i = 0; i < 4; ++i) {
            const int growb = m0 + mh + i * 16 + quad * 4;
            #pragma unroll
            for (int rr = 0; rr < 4; ++rr) {
                const int grow = growb + rr;
                if (grow < M)
                    g[(size_t)grow * HID + gcol] = rtne(acc[i][j][rr]);
            }
        }
    }
}

// h[e] = relu(gs[row[e]] - g[e^1] + b + h0[e]); ROW-MAJOR. One thread per
// (edge-pair, 8-col chunk); a wave = one pair -> contiguous 1KB wave reads.
// In-place on g (thread reads both pair rows before writing both).
__global__ __launch_bounds__(256) void combine_msg(
    const __bf16* __restrict__ g, const __bf16* __restrict__ gs,
    const int* __restrict__ row, const void* __restrict__ bias, int bias_off,
    const __bf16* __restrict__ h0, __bf16* __restrict__ hdst,
    const int* __restrict__ flags)
{
    long idx = (long)blockIdx.x * 256 + threadIdx.x;
    if (idx >= (long)(E_EDGES / 2) * 64) return;
    const int p = (int)(idx >> 6);
    const int k = (int)(idx & 63) * 8;
    const int e0 = 2 * p, e1 = 2 * p + 1;
    const int u0 = row[e0], u1 = row[e1];

    bf16x8 g0 = *(const bf16x8*)(g + (size_t)e0 * HID + k);
    bf16x8 g1 = *(const bf16x8*)(g + (size_t)e1 * HID + k);
    bf16x8 r0 = *(const bf16x8*)(h0 + (size_t)e0 * HID + k);
    bf16x8 r1 = *(const bf16x8*)(h0 + (size_t)e1 * HID + k);
    bf16x8 s0 = *(const bf16x8*)(gs + (size_t)u0 * HID + k);
    bf16x8 s1 = *(const bf16x8*)(gs + (size_t)u1 * HID + k);

    const int f32 = flags[0];
    bf16x8 o0, o1;
    #pragma unroll
    for (int j = 0; j < 8; ++j) {
        const float bv = ldf(bias, bias_off + k + j, f32);
        float v0 = (float)s0[j] - (float)g1[j] + bv + (float)r0[j];
        float v1 = (float)s1[j] - (float)g0[j] + bv + (float)r1[j];
        o0[j] = rtne(v0 > 0.f ? v0 : 0.f);
        o1[j] = rtne(v1 > 0.f ? v1 : 0.f);
    }
    *(bf16x8*)(hdst + (size_t)e0 * HID + k) = o0;
    *(bf16x8*)(hdst + (size_t)e1 * HID + k) = o1;
}

__global__ void bucket_build(const int* __restrict__ col, int* __restrict__ counts,
                             int* __restrict__ buckets, int E)
{
    int e = blockIdx.x * 256 + threadIdx.x;
    if (e >= E) return;
    int c = col[e];
    int p = atomicAdd(&counts[c], 1);
    if (p < CAP) buckets[(size_t)c * CAP + p] = e;
}

// Vectorized segsum, ROW-MAJOR input [E][512]: one thread per (node, 8-col
// chunk); a wave (= one node) reads a contiguous 1KB line per bucket edge.
__global__ __launch_bounds__(256) void segsum8(
    const __bf16* __restrict__ h, const int* __restrict__ counts,
    const int* __restrict__ buckets, __bf16* __restrict__ abf,
    float* __restrict__ af32)
{
    const int nid = blockIdx.x * 4 + (threadIdx.x >> 6);
    const int fc = threadIdx.x & 63;
    if (nid >= N_NODES) return;
    const int k = fc * 8;
    int cnt = counts[nid]; if (cnt > CAP) cnt = CAP;
    const int* bl = buckets + (size_t)nid * CAP;
    float s[8] = {0.f, 0.f, 0.f, 0.f, 0.f, 0.f, 0.f, 0.f};
    for (int i = 0; i < cnt; ++i) {
        const int e = bl[i];
        bf16x8 v = *(const bf16x8*)(h + (size_t)e * HID + k);
        #pragma unroll
        for (int j = 0; j < 8; ++j) s[j] += (float)v[j];
    }
    if (af32) {
        f32x4* out = (f32x4*)(af32 + (size_t)nid * HID + k);
        out[0] = f32x4{s[0], s[1], s[2], s[3]};
        out[1] = f32x4{s[4], s[5], s[6], s[7]};
    } else {
        bf16x8 o;
        #pragma unroll
        for (int j = 0; j < 8; ++j) o[j] = rtne(s[j]);
        *(bf16x8*)(abf + (size_t)nid * HID + k) = o;
    }
}

__global__ void graph_starts(const int* __restrict__ batch, int* __restrict__ gstart, int N, int G)
{
    int n = blockIdx.x * 256 + threadIdx.x;
    if (n >= N) return;
    int b = batch[n];
    if (n == 0) {
        for (int g = 0; g <= b; ++g) gstart[g] = 0;
    } else {
        int pb = batch[n - 1];
        for (int g = pb + 1; g <= b; ++g) gstart[g] = n;
    }
    if (n == N - 1) {
        for (int g = b + 1; g <= G; ++g) gstart[g] = N;
    }
}

__global__ void pool_nodes(const float* __restrict__ hn, const int* __restrict__ gstart,
                           float* __restrict__ Apool)
{
    int g = blockIdx.x;
    int s = gstart[g], e = gstart[g + 1];
    for (int f = threadIdx.x; f < HID; f += 256) {
        float acc = 0.f;
        for (int n = s; n < e; ++n) acc += hn[(size_t)n * HID + f];
        Apool[(size_t)g * HID + f] = acc;
    }
}

// fused ffn: per block 8 graphs; t = relu(Apool@W1+b1); out = t@W2 + b2 (all f32)
__global__ __launch_bounds__(256) void ffn_fused(
    const float* __restrict__ Apool, const void* __restrict__ W1,
    const void* __restrict__ b1, const void* __restrict__ W2,
    const void* __restrict__ b2v, void* __restrict__ outv,
    const int* __restrict__ flags)
{
    __shared__ float sA[8][512];
    __shared__ float t[8][512];
    __shared__ float sW2[512];
    __shared__ float red[4];
    const int tid = threadIdx.x;
    const int g0 = blockIdx.x * 8;
    const int f32 = flags[0];

    for (int i = tid; i < 4096; i += 256)
        sA[i >> 9][i & 511] = Apool[(size_t)g0 * 512 + i];
    for (int n = tid; n < 512; n += 256)
        sW2[n] = ldf(W2, n, f32);
    __syncthreads();

    {
        float acc0[8], acc1[8];
        const float bb0 = ldf(b1, tid, f32);
        const float bb1 = ldf(b1, tid + 256, f32);
        #pragma unroll
        for (int gi = 0; gi < 8; ++gi) { acc0[gi] = bb0; acc1[gi] = bb1; }
        if (f32) {
            const float* Wf = (const float*)W1;
            for (int k = 0; k < 512; ++k) {
                float w0 = Wf[(size_t)k * 512 + tid];
                float w1 = Wf[(size_t)k * 512 + tid + 256];
                #pragma unroll
                for (int gi = 0; gi < 8; ++gi) {
                    float a = sA[gi][k];
                    acc0[gi] += a * w0;
                    acc1[gi] += a * w1;
                }
            }
        } else {
            const __bf16* Wb = (const __bf16*)W1;
            for (int k = 0; k < 512; ++k) {
                float w0 = (float)Wb[(size_t)k * 512 + tid];
                float w1 = (float)Wb[(size_t)k * 512 + tid + 256];
                #pragma unroll
                for (int gi = 0; gi < 8; ++gi) {
                    float a = sA[gi][k];
                    acc0[gi] += a * w0;
                    acc1[gi] += a * w1;
                }
            }
        }
        #pragma unroll
        for (int gi = 0; gi < 8; ++gi) {
            t[gi][tid]       = acc0[gi] > 0.f ? acc0[gi] : 0.f;
            t[gi][tid + 256] = acc1[gi] > 0.f ? acc1[gi] : 0.f;
        }
    }
    __syncthreads();

    const int lane = tid & 63;
    const int w = tid >> 6;
    const float b2 = ldf(b2v, 0, f32);
    for (int gi = 0; gi < 8; ++gi) {
        float p = t[gi][tid] * sW2[tid] + t[gi][tid + 256] * sW2[tid + 256];
        for (int o = 32; o; o >>= 1) p += __shfl_down(p, o, 64);
        if (lane == 0) red[w] = p;
        __syncthreads();
        if (tid == 0) {
            float r = red[0] + red[1] + red[2] + red[3] + b2;
            if (f32) ((float*)outv)[g0 + gi] = r;
            else     ((__bf16*)outv)[g0 + gi] = rtne(r);
        }
        __syncthreads();
    }
}

extern "C" void kernel_launch(void* const* d_in, const int* in_sizes, int n_in,
                              void* d_out, int out_size, void* d_ws, size_t ws_size,
                              hipStream_t stream)
{
    const int E = E_EDGES, NN = N_NODES, G = N_GRAPHS;
    const int CH = E / 4;                        // 25000-row chunks (quarter window)

    char* wsp = (char*)d_ws;
    size_t off = 0;
    auto carve = [&](size_t bytes) -> void* {
        void* p = wsp + off;
        off += (bytes + 511) & ~(size_t)511;
        return p;
    };

    // r6 carve order; state buffer in position 2 (placement-sensitive, r8).
    __bf16* h0    = (__bf16*)carve((size_t)E * HID * 2);   // ROW-MAJOR [E][512]
    // state: try quarter WINDOW (E+CH rows) -> all conv layers use the
    // col-split 2-blocks/CU GEMM (chunked, src!=dst per launch, stream-ordered).
    // Fallback: plain E rows + in-place gemmg1024 (r11 path, 1310us proven).
    const size_t off_state = off;
    __bf16* stateb = (__bf16*)carve((size_t)(E + CH) * HID * 2);
    size_t off_try = 0;  // computed after all carves
    __bf16* abuf  = (__bf16*)carve((size_t)NN * HID * 2);  // row-major; gs each layer
    float*  Apool = (float*) carve((size_t)G * HID * 4);
    __bf16* WTih  = (__bf16*)carve((size_t)512 * 160 * 2);
    __bf16* WTil  = (__bf16*)carve((size_t)512 * 160 * 2);
    __bf16* WTch  = (__bf16*)carve((size_t)4 * 512 * 512 * 2);
    __bf16* WTcl  = (__bf16*)carve((size_t)4 * 512 * 512 * 2);
    __bf16* WTqh  = (__bf16*)carve((size_t)512 * 672 * 2);
    __bf16* WTql  = (__bf16*)carve((size_t)512 * 672 * 2);
    int*    ei32  = (int*)   carve((size_t)2 * E * 4);
    int*    b32   = (int*)   carve((size_t)NN * 4);
    int*    counts= (int*)   carve((size_t)NN * 4);
    int*    bucket= (int*)   carve((size_t)NN * CAP * 4);
    int*    gstart= (int*)   carve((size_t)(G + 1) * 4);
    int*    flags = (int*)   carve(2 * 4);
    off_try = off;

    bool haswin = (off_try <= ws_size);
    if (!haswin) {
        // re-carve with plain E-row state (shift everything after it back)
        off = off_state;
        stateb = (__bf16*)carve((size_t)E * HID * 2);
        abuf  = (__bf16*)carve((size_t)NN * HID * 2);
        Apool = (float*) carve((size_t)G * HID * 4);
        WTih  = (__bf16*)carve((size_t)512 * 160 * 2);
        WTil  = (__bf16*)carve((size_t)512 * 160 * 2);
        WTch  = (__bf16*)carve((size_t)4 * 512 * 512 * 2);
        WTcl  = (__bf16*)carve((size_t)4 * 512 * 512 * 2);
        WTqh  = (__bf16*)carve((size_t)512 * 672 * 2);
        WTql  = (__bf16*)carve((size_t)512 * 672 * 2);
        ei32  = (int*)   carve((size_t)2 * E * 4);
        b32   = (int*)   carve((size_t)NN * 4);
        counts= (int*)   carve((size_t)NN * 4);
        bucket= (int*)   carve((size_t)NN * CAP * 4);
        gstart= (int*)   carve((size_t)(G + 1) * 4);
        flags = (int*)   carve(2 * 4);
        if (off > ws_size) {  // clean fail instead of faulting
            hipMemsetAsync(d_out, 0, (size_t)out_size * 4, stream);
            return;
        }
    }

    // aliases into provably-dead regions of the state buffer
    __bf16* Aih = stateb;                         // E*160 bf16 x2; dead before layer-0 output
    __bf16* Ail = stateb + (size_t)E * 160;
    __bf16* Aqh = stateb;                         // state dead after final segsum
    __bf16* Aql = stateb + (size_t)NN * 672;
    float*  hn   = (float*)h0;                    // NN*512 f32; h0 dead after layer-3 combine
    float*  sfin = (float*)((char*)h0 + (size_t)NN * HID * 4);  // NN*512 f32

    auto cdiv = [](long a, long b) { return (int)((a + b - 1) / b); };

    probe_dtypes<<<1, 256, 0, stream>>>((const unsigned*)d_in[0], (const unsigned*)d_in[1], flags);
    to_int32<<<cdiv((long)2 * E, 256), 256, 0, stream>>>(d_in[1], ei32, (long)2 * E, flags);
    to_int32<<<cdiv(NN, 256), 256, 0, stream>>>(d_in[3], b32, NN, flags);

    const int* row = ei32;
    const int* col = ei32 + E;

    hipMemsetAsync(counts, 0, (size_t)NN * 4, stream);

    split_transpose_t<<<dim3(8, 3, 1), 256, 0, stream>>>(d_in[4], WTih, WTil, 147, 512, 160, 0, flags);
    split_transpose_t<<<dim3(8, 8, 4), 256, 0, stream>>>(d_in[6], WTch, WTcl, 512, 512, 512, 0, flags);
    split_transpose_t<<<dim3(8, 11, 1), 256, 0, stream>>>(d_in[8], WTqh, WTql, 645, 512, 672, 0, flags);

    bucket_build<<<cdiv(E, 256), 256, 0, stream>>>(col, counts, bucket, E);

    // edge init: h0 = relu([x[row], ea] @ W_ei + b_ei) -> ROW-MAJOR (3-term)
    build_Ainit_split8<<<cdiv((long)E * 20, 256), 256, 0, stream>>>(d_in[0], d_in[2], row, Aih, Ail, flags);
    gemm3w<<<cdiv(E, 128), 1024, 0, stream>>>(Aih, Ail, WTih, WTil, d_in[5], h0, 0, E, 160, flags);

    // DMPNN layers: g = h@W (1-term); gs = segsum(g); h = relu(gs[row] - g[rev] + b + h0)
    const long ncomb = (long)(E / 2) * 64;
    size_t o = 0;   // state row offset (window path alternates 0 <-> CH)
    for (int l = 0; l < 4; ++l) {
        const __bf16* Wh = WTch + (size_t)l * 512 * 512;
        size_t go;
        if (l == 0) {
            gemmg512<<<dim3(cdiv(E, 128), 2), 512, 0, stream>>>(h0, Wh, stateb, E);
            go = 0;
        } else if (haswin) {
            if (o == 0) {       // state rows [0,E): descending chunks -> g at CH
                for (int c = 3; c >= 0; --c)
                    gemmg512<<<dim3(cdiv(CH, 128), 2), 512, 0, stream>>>(
                        stateb + (size_t)c * CH * HID, Wh,
                        stateb + (size_t)(c + 1) * CH * HID, CH);
                go = CH;
            } else {            // state rows [CH,E+CH): ascending chunks -> g at 0
                for (int c = 0; c < 4; ++c)
                    gemmg512<<<dim3(cdiv(CH, 128), 2), 512, 0, stream>>>(
                        stateb + (size_t)(CH + c * CH) * HID, Wh,
                        stateb + (size_t)c * CH * HID, CH);
                go = 0;
            }
        } else {
            gemmg1024<<<cdiv(E, 128), 1024, 0, stream>>>(stateb, Wh, stateb, E);
            go = 0;
        }
        segsum8<<<cdiv(NN, 4), 256, 0, stream>>>(stateb + go * HID, counts, bucket, abuf, nullptr);
        combine_msg<<<cdiv(ncomb, 256), 256, 0, stream>>>(
            stateb + go * HID, abuf, row, d_in[7], l * 512, h0, stateb + go * HID, flags);
        o = go;
    }

    // final aggregation (f32) + e2n (wide 3-term GEMM, f32 row-major out)
    segsum8<<<cdiv(NN, 4), 256, 0, stream>>>(stateb + o * HID, counts, bucket, nullptr, sfin);
    build_Ae2n_split8<<<cdiv((long)NN * 84, 256), 256, 0, stream>>>(d_in[0], sfin, Aqh, Aql, flags);
    gemm3w<<<cdiv(NN, 128), 1024, 0, stream>>>(Aqh, Aql, WTqh, WTql, d_in[9], hn, 1, NN, 672, flags);

    // pool + fused ffn (all f32)
    graph_starts<<<cdiv(NN, 256), 256, 0, stream>>>(b32, gstart, NN, G);
    pool_nodes<<<G, 256, 0, stream>>>(hn, gstart, Apool);
    ffn_fused<<<G / 8, 256, 0, stream>>>(Apool, d_in[10], d_in[11], d_in[12], d_in[13], d_out, flags);
}

// Round 14
// 1226.702 us; speedup vs baseline: 1.4925x; 1.0335x over previous
//
#include <hip/hip_runtime.h>

typedef __bf16 bf16x8 __attribute__((ext_vector_type(8)));
typedef float  f32x4  __attribute__((ext_vector_type(4)));

#define E_EDGES 100000
#define N_NODES 25000
#define N_GRAPHS 2048
#define HID 512
#define CAP 32

__device__ __forceinline__ void gload_lds16(const void* g, void* l) {
    __builtin_amdgcn_global_load_lds(
        (const __attribute__((address_space(1))) void*)g,
        (__attribute__((address_space(3))) void*)l, 16, 0, 0);
}

__device__ __forceinline__ __bf16 rtne(float x) {
    union { unsigned short s; __bf16 b; } u;
    unsigned v = __float_as_uint(x);
    u.s = (unsigned short)((v + 0x7FFF + ((v >> 16) & 1)) >> 16);
    return u.b;
}

__device__ __forceinline__ void split2(float x, __bf16& hi, __bf16& lo) {
    hi = rtne(x);
    lo = rtne(x - (float)hi);
}

__device__ __forceinline__ float ldf(const void* p, long i, int f32) {
    return f32 ? ((const float*)p)[i] : (float)(((const __bf16*)p)[i]);
}

// flags[0]=1 if float inputs are f32 (else bf16); flags[1]=1 if int inputs are i64
__global__ void probe_dtypes(const unsigned* __restrict__ xr, const unsigned* __restrict__ eir,
                             int* __restrict__ flags)
{
    __shared__ int cfp, ci;
    if (threadIdx.x == 0) { cfp = 0; ci = 0; }
    __syncthreads();
    int lc = 0;
    for (int i = threadIdx.x; i < 1024; i += 256) {
        unsigned elo = (xr[i] >> 7) & 0xFFu;
        if (elo > 140u) lc++;
    }
    atomicAdd(&cfp, lc);
    int ln = 0;
    for (int i = threadIdx.x; i < 512; i += 256) {
        if (eir[2 * i + 1] != 0u) ln++;
    }
    atomicAdd(&ci, ln);
    __syncthreads();
    if (threadIdx.x == 0) {
        flags[0] = (cfp > 100) ? 1 : 0;
        flags[1] = (ci < 256) ? 1 : 0;
    }
}

__global__ void to_int32(const void* __restrict__ src, int* __restrict__ dst, long n,
                         const int* __restrict__ flags)
{
    long i = (long)blockIdx.x * 256 + threadIdx.x;
    if (i >= n) return;
    dst[i] = flags[1] ? (int)((const long long*)src)[i] : ((const int*)src)[i];
}

// Tiled transpose+split: WThi/WTlo[n,k] = split(W[krow0 + z*512 + k, n]), zero-pad to Kpad.
__global__ __launch_bounds__(256) void split_transpose_t(
    const void* __restrict__ W, __bf16* __restrict__ Whi, __bf16* __restrict__ Wlo,
    int Ksrc, int N, int Kpad, int krow0, const int* __restrict__ flags)
{
    __shared__ float tile[64][65];
    const int z = blockIdx.z;
    const int nb = blockIdx.x * 64;
    const int kb = blockIdx.y * 64;
    const int f32m = flags[0];
    const int lx = threadIdx.x & 63;
    const size_t dsto = (size_t)z * N * Kpad;
    const int kro = krow0 + z * 512;

    for (int rr = threadIdx.x >> 6; rr < 64; rr += 4) {
        const int k = kb + rr;
        const int n = nb + lx;
        float v = 0.f;
        if (k < Ksrc && n < N) v = ldf(W, (size_t)(kro + k) * N + n, f32m);
        tile[rr][lx] = v;
    }
    __syncthreads();
    for (int rr = threadIdx.x >> 6; rr < 64; rr += 4) {
        const int n = nb + rr;
        const int k = kb + lx;
        if (n < N && k < Kpad) {
            __bf16 hi, lo; split2(tile[lx][rr], hi, lo);
            Whi[dsto + (size_t)n * Kpad + k] = hi;
            Wlo[dsto + (size_t)n * Kpad + k] = lo;
        }
    }
}

// A_init[e,0:160] = [x[row[e],0:133], ea[e,0:14], 0] -> hi/lo; one thread per 8-f chunk
__global__ void build_Ainit_split8(const void* __restrict__ x, const void* __restrict__ ea,
                                   const int* __restrict__ row, __bf16* __restrict__ Ah,
                                   __bf16* __restrict__ Al, const int* __restrict__ flags)
{
    long idx = (long)blockIdx.x * 256 + threadIdx.x;
    if (idx >= (long)E_EDGES * 20) return;
    const int e = (int)(idx / 20), c = (int)(idx % 20);
    const int f0 = c * 8;
    const int f32m = flags[0];
    const int r = row[e];
    bf16x8 oh, ol;
    #pragma unroll
    for (int j = 0; j < 8; ++j) {
        const int f = f0 + j;
        float v = 0.f;
        if (f < 133)      v = ldf(x, (size_t)r * 133 + f, f32m);
        else if (f < 147) v = ldf(ea, (size_t)e * 14 + (f - 133), f32m);
        __bf16 hi, lo; split2(v, hi, lo);
        oh[j] = hi; ol[j] = lo;
    }
    *(bf16x8*)(Ah + (size_t)e * 160 + f0) = oh;
    *(bf16x8*)(Al + (size_t)e * 160 + f0) = ol;
}

// A_e2n[n,0:672] = [x[n,0:133], s_f32[n,0:512], 0] -> hi/lo; one thread per 8-f chunk
__global__ void build_Ae2n_split8(const void* __restrict__ x, const float* __restrict__ s,
                                  __bf16* __restrict__ Ah, __bf16* __restrict__ Al,
                                  const int* __restrict__ flags)
{
    long idx = (long)blockIdx.x * 256 + threadIdx.x;
    if (idx >= (long)N_NODES * 84) return;
    const int n = (int)(idx / 84), c = (int)(idx % 84);
    const int f0 = c * 8;
    const int f32m = flags[0];
    bf16x8 oh, ol;
    #pragma unroll
    for (int j = 0; j < 8; ++j) {
        const int f = f0 + j;
        float v = 0.f;
        if (f < 133)      v = ldf(x, (size_t)n * 133 + f, f32m);
        else if (f < 645) v = s[(size_t)n * HID + (f - 133)];
        __bf16 hi, lo; split2(v, hi, lo);
        oh[j] = hi; ol[j] = lo;
    }
    *(bf16x8*)(Ah + (size_t)n * 672 + f0) = oh;
    *(bf16x8*)(Al + (size_t)n * 672 + f0) = ol;
}

// Wide split-precision GEMM: C[M,512] = relu(A @ BT^T + bias), 3-term MFMA.
// LDS-staged epilogue (r12): 64B-granule row-major writes.
__global__ __launch_bounds__(1024) void gemm3w(
    const __bf16* __restrict__ Ah, const __bf16* __restrict__ Al,
    const __bf16* __restrict__ Bh, const __bf16* __restrict__ Bl,
    const void* __restrict__ bias,
    void* __restrict__ C, int out_f32, int M, int K, const int* __restrict__ flags)
{
    __shared__ __bf16 lAh[128 * 32];
    __shared__ __bf16 lAl[128 * 32];
    __shared__ __bf16 lBh[512 * 32];
    __shared__ char   lEpi[16 * 4864];   // per-wave epilogue staging (77.8KB)

    const int m0 = blockIdx.x * 128;
    const int tid = threadIdx.x;
    const int w = tid >> 6;
    const int lane = tid & 63;

    const int ac = tid & 511;
    int arow = m0 + (ac >> 2); if (arow >= M) arow = M - 1;
    const int akc = (ac & 3) << 3;
    const __bf16* Asrc = (tid < 512) ? Ah : Al;
    const size_t ag = (size_t)arow * K + akc;
    __bf16* aw = ((tid < 512) ? lAh : lAl) + (ac >> 2) * 32 + akc;

    const size_t bg0 = (size_t)(tid >> 2) * K + ((tid & 3) << 3);
    const size_t bg1 = (size_t)((tid + 1024) >> 2) * K + (((tid + 1024) & 3) << 3);
    __bf16* wB0 = lBh + (size_t)tid * 8;
    __bf16* wB1 = lBh + (size_t)(tid + 1024) * 8;

    const int mh = (w >> 3) * 64;
    const int nq = (w & 7) * 64;
    const int c16 = lane & 15;
    const int quad = lane >> 4;

    const __bf16* blp = Bl + (size_t)(nq + c16) * K + quad * 8;

    f32x4 acc[4][4] = {};

    for (int k0 = 0; k0 < K; k0 += 32) {
        gload_lds16(Asrc + ag + k0, aw);
        gload_lds16(Bh + bg0 + k0, wB0);
        gload_lds16(Bh + bg1 + k0, wB1);
        __syncthreads();

        bf16x8 bl[4];
        #pragma unroll
        for (int j = 0; j < 4; ++j)
            bl[j] = *(const bf16x8*)(blp + (size_t)(j * 16) * K + k0);

        bf16x8 ah[4], al[4];
        #pragma unroll
        for (int i = 0; i < 4; ++i) {
            ah[i] = *(const bf16x8*)(lAh + (mh + i * 16 + c16) * 32 + quad * 8);
            al[i] = *(const bf16x8*)(lAl + (mh + i * 16 + c16) * 32 + quad * 8);
        }
        #pragma unroll
        for (int j = 0; j < 4; ++j) {
            bf16x8 bh = *(const bf16x8*)(lBh + (nq + j * 16 + c16) * 32 + quad * 8);
            #pragma unroll
            for (int i = 0; i < 4; ++i) {
                acc[i][j] = __builtin_amdgcn_mfma_f32_16x16x32_bf16(ah[i], bh, acc[i][j], 0, 0, 0);
                acc[i][j] = __builtin_amdgcn_mfma_f32_16x16x32_bf16(al[i], bh, acc[i][j], 0, 0, 0);
                acc[i][j] = __builtin_amdgcn_mfma_f32_16x16x32_bf16(ah[i], bl[j], acc[i][j], 0, 0, 0);
            }
        }
        __syncthreads();
    }

    const int f32 = flags[0];
    if (out_f32) {
        float* epf = (float*)(lEpi + (size_t)w * 4864);   // [64][19] f32
        float* Cf = (float*)C;
        #pragma unroll
        for (int j = 0; j < 4; ++j) {
            const float bv = ldf(bias, nq + j * 16 + c16, f32);
            #pragma unroll
            for (int i = 0; i < 4; ++i)
                #pragma unroll
                for (int rr = 0; rr < 4; ++rr) {
                    float v = acc[i][j][rr] + bv;
                    epf[(i * 16 + quad * 4 + rr) * 19 + c16] = v > 0.f ? v : 0.f;
                }
            #pragma unroll
            for (int it = 0; it < 4; ++it) {
                const int c = it * 64 + lane;
                const int rowL = c >> 2, qc = c & 3;
                f32x4 v = *(const f32x4*)&epf[rowL * 19 + qc * 4];
                const int grow = m0 + mh + rowL;
                if (grow < M)
                    *(f32x4*)(Cf + (size_t)grow * HID + nq + j * 16 + qc * 4) = v;
            }
        }
    } else {
        __bf16* ep = (__bf16*)(lEpi + (size_t)w * 4864);  // [64][34] bf16
        __bf16* Cb = (__bf16*)C;
        #pragma unroll
        for (int jp = 0; jp < 2; ++jp) {
            #pragma unroll
            for (int j2 = 0; j2 < 2; ++j2) {
                const int j = jp * 2 + j2;
                const float bv = ldf(bias, nq + j * 16 + c16, f32);
                #pragma unroll
                for (int i = 0; i < 4; ++i)
                    #pragma unroll
                    for (int rr = 0; rr < 4; ++rr) {
                        float v = acc[i][j][rr] + bv;
                        ep[(i * 16 + quad * 4 + rr) * 34 + j2 * 16 + c16] = rtne(v > 0.f ? v : 0.f);
                    }
            }
            #pragma unroll
            for (int it = 0; it < 4; ++it) {
                const int c = it * 64 + lane;
                const int rowL = c >> 2, qc = c & 3;
                bf16x8 v = *(const bf16x8*)&ep[rowL * 34 + qc * 8];
                const int grow = m0 + mh + rowL;
                if (grow < M)
                    *(bf16x8*)(Cb + (size_t)grow * HID + nq + jp * 32 + qc * 8) = v;
            }
        }
    }
}

// Streaming GEMM g = h @ Wh^T, 1-TERM, ROW-MAJOR. 512-thr / BM=128 / BN=256
// col-split: 2 blocks/CU. REQUIRES src rows != dst rows — satisfied by the
// sliding-window chunking (dst = the free CH-row band, stream-ordered).
// LDS-staged epilogue (64B-granule writes).
__global__ __launch_bounds__(512, 4) void gemmg512(
    const __bf16* __restrict__ hsrc, const __bf16* __restrict__ Bh,
    __bf16* __restrict__ g, int M)
{
    __shared__ __bf16 lA[128 * 32];        //  8KB
    __shared__ __bf16 lB[256 * 32];        // 16KB
    __shared__ __bf16 lEp[8 * 64 * 34];    // 34.8KB (total 59.4KB -> 2 blocks OK)

    const int m0 = blockIdx.x * 128;
    const int nc = blockIdx.y * 256;
    const int tid = threadIdx.x;
    const int w = tid >> 6;
    const int lane = tid & 63;

    int arow = m0 + (tid >> 2); if (arow >= M) arow = M - 1;
    const size_t ag = (size_t)arow * HID + ((tid & 3) << 3);

    const int c0 = tid, c1 = tid + 512;
    const size_t bg0 = (size_t)(nc + (c0 >> 2)) * HID + ((c0 & 3) << 3);
    const size_t bg1 = (size_t)(nc + (c1 >> 2)) * HID + ((c1 & 3) << 3);

    const int mh = (w >> 2) * 64;
    const int nqw = (w & 3) * 64;
    const int c16 = lane & 15;
    const int quad = lane >> 4;

    f32x4 acc[4][4] = {};

    for (int k0 = 0; k0 < HID; k0 += 32) {
        gload_lds16(hsrc + ag + k0, &lA[tid * 8]);
        gload_lds16(Bh + bg0 + k0, &lB[c0 * 8]);
        gload_lds16(Bh + bg1 + k0, &lB[c1 * 8]);
        __syncthreads();

        bf16x8 ah[4];
        #pragma unroll
        for (int i = 0; i < 4; ++i)
            ah[i] = *(const bf16x8*)&lA[(mh + i * 16 + c16) * 32 + quad * 8];

        #pragma unroll
        for (int j = 0; j < 4; ++j) {
            bf16x8 bh = *(const bf16x8*)&lB[(nqw + j * 16 + c16) * 32 + quad * 8];
            #pragma unroll
            for (int i = 0; i < 4; ++i)
                acc[i][j] = __builtin_amdgcn_mfma_f32_16x16x32_bf16(ah[i], bh, acc[i][j], 0, 0, 0);
        }
        __syncthreads();
    }

    __bf16* ep = lEp + (size_t)w * (64 * 34);
    #pragma unroll
    for (int jp = 0; jp < 2; ++jp) {
        #pragma unroll
        for (int j2 = 0; j2 < 2; ++j2) {
            const int j = jp * 2 + j2;
            #pragma unroll
            for (int i = 0; i < 4; ++i)
                #pragma unroll
                for (int rr = 0; rr < 4; ++rr)
                    ep[(i * 16 + quad * 4 + rr) * 34 + j2 * 16 + c16] = rtne(acc[i][j][rr]);
        }
        #pragma unroll
        for (int it = 0; it < 4; ++it) {
            const int c = it * 64 + lane;
            const int rowL = c >> 2, qc = c & 3;
            bf16x8 v = *(const bf16x8*)&ep[rowL * 34 + qc * 8];
            const int grow = m0 + mh + rowL;
            if (grow < M)
                *(bf16x8*)(g + (size_t)grow * HID + nc + nqw + jp * 32 + qc * 8) = v;
        }
    }
}

// h[e] = relu(gs[row[e]] - g[e^1] + b + h0[e]); ROW-MAJOR. One thread per
// (edge-pair, 8-col chunk); a wave = one pair -> contiguous 1KB wave reads.
// In-place on g (thread reads both pair rows before writing both).
__global__ __launch_bounds__(256) void combine_msg(
    const __bf16* __restrict__ g, const __bf16* __restrict__ gs,
    const int* __restrict__ row, const void* __restrict__ bias, int bias_off,
    const __bf16* __restrict__ h0, __bf16* __restrict__ hdst,
    const int* __restrict__ flags)
{
    long idx = (long)blockIdx.x * 256 + threadIdx.x;
    if (idx >= (long)(E_EDGES / 2) * 64) return;
    const int p = (int)(idx >> 6);
    const int k = (int)(idx & 63) * 8;
    const int e0 = 2 * p, e1 = 2 * p + 1;
    const int u0 = row[e0], u1 = row[e1];

    bf16x8 g0 = *(const bf16x8*)(g + (size_t)e0 * HID + k);
    bf16x8 g1 = *(const bf16x8*)(g + (size_t)e1 * HID + k);
    bf16x8 r0 = *(const bf16x8*)(h0 + (size_t)e0 * HID + k);
    bf16x8 r1 = *(const bf16x8*)(h0 + (size_t)e1 * HID + k);
    bf16x8 s0 = *(const bf16x8*)(gs + (size_t)u0 * HID + k);
    bf16x8 s1 = *(const bf16x8*)(gs + (size_t)u1 * HID + k);

    const int f32 = flags[0];
    bf16x8 o0, o1;
    #pragma unroll
    for (int j = 0; j < 8; ++j) {
        const float bv = ldf(bias, bias_off + k + j, f32);
        float v0 = (float)s0[j] - (float)g1[j] + bv + (float)r0[j];
        float v1 = (float)s1[j] - (float)g0[j] + bv + (float)r1[j];
        o0[j] = rtne(v0 > 0.f ? v0 : 0.f);
        o1[j] = rtne(v1 > 0.f ? v1 : 0.f);
    }
    *(bf16x8*)(hdst + (size_t)e0 * HID + k) = o0;
    *(bf16x8*)(hdst + (size_t)e1 * HID + k) = o1;
}

__global__ void bucket_build(const int* __restrict__ col, int* __restrict__ counts,
                             int* __restrict__ buckets, int E)
{
    int e = blockIdx.x * 256 + threadIdx.x;
    if (e >= E) return;
    int c = col[e];
    int p = atomicAdd(&counts[c], 1);
    if (p < CAP) buckets[(size_t)c * CAP + p] = e;
}

// Vectorized segsum, ROW-MAJOR input [E][512]: one thread per (node, 8-col
// chunk); a wave (= one node) reads a contiguous 1KB line per bucket edge.
__global__ __launch_bounds__(256) void segsum8(
    const __bf16* __restrict__ h, const int* __restrict__ counts,
    const int* __restrict__ buckets, __bf16* __restrict__ abf,
    float* __restrict__ af32)
{
    const int nid = blockIdx.x * 4 + (threadIdx.x >> 6);
    const int fc = threadIdx.x & 63;
    if (nid >= N_NODES) return;
    const int k = fc * 8;
    int cnt = counts[nid]; if (cnt > CAP) cnt = CAP;
    const int* bl = buckets + (size_t)nid * CAP;
    float s[8] = {0.f, 0.f, 0.f, 0.f, 0.f, 0.f, 0.f, 0.f};
    for (int i = 0; i < cnt; ++i) {
        const int e = bl[i];
        bf16x8 v = *(const bf16x8*)(h + (size_t)e * HID + k);
        #pragma unroll
        for (int j = 0; j < 8; ++j) s[j] += (float)v[j];
    }
    if (af32) {
        f32x4* out = (f32x4*)(af32 + (size_t)nid * HID + k);
        out[0] = f32x4{s[0], s[1], s[2], s[3]};
        out[1] = f32x4{s[4], s[5], s[6], s[7]};
    } else {
        bf16x8 o;
        #pragma unroll
        for (int j = 0; j < 8; ++j) o[j] = rtne(s[j]);
        *(bf16x8*)(abf + (size_t)nid * HID + k) = o;
    }
}

__global__ void graph_starts(const int* __restrict__ batch, int* __restrict__ gstart, int N, int G)
{
    int n = blockIdx.x * 256 + threadIdx.x;
    if (n >= N) return;
    int b = batch[n];
    if (n == 0) {
        for (int g = 0; g <= b; ++g) gstart[g] = 0;
    } else {
        int pb = batch[n - 1];
        for (int g = pb + 1; g <= b; ++g) gstart[g] = n;
    }
    if (n == N - 1) {
        for (int g = b + 1; g <= G; ++g) gstart[g] = N;
    }
}

__global__ void pool_nodes(const float* __restrict__ hn, const int* __restrict__ gstart,
                           float* __restrict__ Apool)
{
    int g = blockIdx.x;
    int s = gstart[g], e = gstart[g + 1];
    for (int f = threadIdx.x; f < HID; f += 256) {
        float acc = 0.f;
        for (int n = s; n < e; ++n) acc += hn[(size_t)n * HID + f];
        Apool[(size_t)g * HID + f] = acc;
    }
}

// fused ffn: per block 8 graphs; t = relu(Apool@W1+b1); out = t@W2 + b2 (all f32)
__global__ __launch_bounds__(256) void ffn_fused(
    const float* __restrict__ Apool, const void* __restrict__ W1,
    const void* __restrict__ b1, const void* __restrict__ W2,
    const void* __restrict__ b2v, void* __restrict__ outv,
    const int* __restrict__ flags)
{
    __shared__ float sA[8][512];
    __shared__ float t[8][512];
    __shared__ float sW2[512];
    __shared__ float red[4];
    const int tid = threadIdx.x;
    const int g0 = blockIdx.x * 8;
    const int f32 = flags[0];

    for (int i = tid; i < 4096; i += 256)
        sA[i >> 9][i & 511] = Apool[(size_t)g0 * 512 + i];
    for (int n = tid; n < 512; n += 256)
        sW2[n] = ldf(W2, n, f32);
    __syncthreads();

    {
        float acc0[8], acc1[8];
        const float bb0 = ldf(b1, tid, f32);
        const float bb1 = ldf(b1, tid + 256, f32);
        #pragma unroll
        for (int gi = 0; gi < 8; ++gi) { acc0[gi] = bb0; acc1[gi] = bb1; }
        if (f32) {
            const float* Wf = (const float*)W1;
            for (int k = 0; k < 512; ++k) {
                float w0 = Wf[(size_t)k * 512 + tid];
                float w1 = Wf[(size_t)k * 512 + tid + 256];
                #pragma unroll
                for (int gi = 0; gi < 8; ++gi) {
                    float a = sA[gi][k];
                    acc0[gi] += a * w0;
                    acc1[gi] += a * w1;
                }
            }
        } else {
            const __bf16* Wb = (const __bf16*)W1;
            for (int k = 0; k < 512; ++k) {
                float w0 = (float)Wb[(size_t)k * 512 + tid];
                float w1 = (float)Wb[(size_t)k * 512 + tid + 256];
                #pragma unroll
                for (int gi = 0; gi < 8; ++gi) {
                    float a = sA[gi][k];
                    acc0[gi] += a * w0;
                    acc1[gi] += a * w1;
                }
            }
        }
        #pragma unroll
        for (int gi = 0; gi < 8; ++gi) {
            t[gi][tid]       = acc0[gi] > 0.f ? acc0[gi] : 0.f;
            t[gi][tid + 256] = acc1[gi] > 0.f ? acc1[gi] : 0.f;
        }
    }
    __syncthreads();

    const int lane = tid & 63;
    const int w = tid >> 6;
    const float b2 = ldf(b2v, 0, f32);
    for (int gi = 0; gi < 8; ++gi) {
        float p = t[gi][tid] * sW2[tid] + t[gi][tid + 256] * sW2[tid + 256];
        for (int o = 32; o; o >>= 1) p += __shfl_down(p, o, 64);
        if (lane == 0) red[w] = p;
        __syncthreads();
        if (tid == 0) {
            float r = red[0] + red[1] + red[2] + red[3] + b2;
            if (f32) ((float*)outv)[g0 + gi] = r;
            else     ((__bf16*)outv)[g0 + gi] = rtne(r);
        }
        __syncthreads();
    }
}

extern "C" void kernel_launch(void* const* d_in, const int* in_sizes, int n_in,
                              void* d_out, int out_size, void* d_ws, size_t ws_size,
                              hipStream_t stream)
{
    const int E = E_EDGES, NN = N_NODES, G = N_GRAPHS;
    const int CH = E / 4;                        // 25000-row chunks / band size

    char* wsp = (char*)d_ws;
    size_t off = 0;
    auto carve = [&](size_t bytes) -> void* {
        void* p = wsp + off;
        off += (bytes + 511) & ~(size_t)511;
        return p;
    };

    // Sliding-window state: (E+CH) rows. The CH-row free band doubles as the
    // gs buffer each layer (it is exactly NN*512 bf16 = 25.6MB), so abuf is
    // GONE and total footprint == the proven r13 fallback footprint.
    __bf16* h0     = (__bf16*)carve((size_t)E * HID * 2);           // ROW-MAJOR [E][512]
    __bf16* stateb = (__bf16*)carve((size_t)(E + CH) * HID * 2);    // window
    float*  Apool = (float*) carve((size_t)G * HID * 4);
    __bf16* WTih  = (__bf16*)carve((size_t)512 * 160 * 2);
    __bf16* WTil  = (__bf16*)carve((size_t)512 * 160 * 2);
    __bf16* WTch  = (__bf16*)carve((size_t)4 * 512 * 512 * 2);
    __bf16* WTcl  = (__bf16*)carve((size_t)4 * 512 * 512 * 2);
    __bf16* WTqh  = (__bf16*)carve((size_t)512 * 672 * 2);
    __bf16* WTql  = (__bf16*)carve((size_t)512 * 672 * 2);
    int*    ei32  = (int*)   carve((size_t)2 * E * 4);
    int*    b32   = (int*)   carve((size_t)NN * 4);
    int*    counts= (int*)   carve((size_t)NN * 4);
    int*    bucket= (int*)   carve((size_t)NN * CAP * 4);
    int*    gstart= (int*)   carve((size_t)(G + 1) * 4);
    int*    flags = (int*)   carve(2 * 4);

    // aliases into provably-dead regions of the state buffer
    __bf16* Aih = stateb;                         // E*160 bf16 x2 (64MB); dead before layer-0 output
    __bf16* Ail = stateb + (size_t)E * 160;
    __bf16* Aqh = stateb;                         // state dead after final segsum
    __bf16* Aql = stateb + (size_t)NN * 672;
    float*  hn   = (float*)h0;                    // NN*512 f32; h0 dead after layer-3 combine
    float*  sfin = (float*)((char*)h0 + (size_t)NN * HID * 4);  // NN*512 f32

    if (off > ws_size) {  // clean fail instead of faulting
        hipMemsetAsync(d_out, 0, (size_t)out_size * 4, stream);
        return;
    }

    auto cdiv = [](long a, long b) { return (int)((a + b - 1) / b); };

    probe_dtypes<<<1, 256, 0, stream>>>((const unsigned*)d_in[0], (const unsigned*)d_in[1], flags);
    to_int32<<<cdiv((long)2 * E, 256), 256, 0, stream>>>(d_in[1], ei32, (long)2 * E, flags);
    to_int32<<<cdiv(NN, 256), 256, 0, stream>>>(d_in[3], b32, NN, flags);

    const int* row = ei32;
    const int* col = ei32 + E;

    hipMemsetAsync(counts, 0, (size_t)NN * 4, stream);

    split_transpose_t<<<dim3(8, 3, 1), 256, 0, stream>>>(d_in[4], WTih, WTil, 147, 512, 160, 0, flags);
    split_transpose_t<<<dim3(8, 8, 4), 256, 0, stream>>>(d_in[6], WTch, WTcl, 512, 512, 512, 0, flags);
    split_transpose_t<<<dim3(8, 11, 1), 256, 0, stream>>>(d_in[8], WTqh, WTql, 645, 512, 672, 0, flags);

    bucket_build<<<cdiv(E, 256), 256, 0, stream>>>(col, counts, bucket, E);

    // edge init: h0 = relu([x[row], ea] @ W_ei + b_ei) -> ROW-MAJOR (3-term)
    build_Ainit_split8<<<cdiv((long)E * 20, 256), 256, 0, stream>>>(d_in[0], d_in[2], row, Aih, Ail, flags);
    gemm3w<<<cdiv(E, 128), 1024, 0, stream>>>(Aih, Ail, WTih, WTil, d_in[5], h0, 0, E, 160, flags);

    // DMPNN layers: g = h@W (1-term, col-split 2-blocks/CU via sliding window);
    // gs = segsum(g) -> free band; h = relu(gs[row] - g[rev] + b + h0) in-place.
    const long ncomb = (long)(E / 2) * 64;
    size_t o = 0;   // state row offset (alternates 0 <-> CH)
    for (int l = 0; l < 4; ++l) {
        const __bf16* Wh = WTch + (size_t)l * 512 * 512;
        size_t go, bo;   // g offset, band offset
        if (l == 0) {
            gemmg512<<<dim3(cdiv(E, 128), 2), 512, 0, stream>>>(h0, Wh, stateb, E);
            go = 0; bo = (size_t)E;
        } else if (o == 0) {
            // state rows [0,E): descending chunks -> g at CH, band at 0
            for (int c = 3; c >= 0; --c)
                gemmg512<<<dim3(cdiv(CH, 128), 2), 512, 0, stream>>>(
                    stateb + (size_t)c * CH * HID, Wh,
                    stateb + (size_t)(c + 1) * CH * HID, CH);
            go = CH; bo = 0;
        } else {
            // state rows [CH,E+CH): ascending chunks -> g at 0, band at E
            for (int c = 0; c < 4; ++c)
                gemmg512<<<dim3(cdiv(CH, 128), 2), 512, 0, stream>>>(
                    stateb + (size_t)(CH + c * CH) * HID, Wh,
                    stateb + (size_t)c * CH * HID, CH);
            go = 0; bo = (size_t)E;
        }
        __bf16* gs = stateb + bo * HID;
        segsum8<<<cdiv(NN, 4), 256, 0, stream>>>(stateb + go * HID, counts, bucket, gs, nullptr);
        combine_msg<<<cdiv(ncomb, 256), 256, 0, stream>>>(
            stateb + go * HID, gs, row, d_in[7], l * 512, h0, stateb + go * HID, flags);
        o = go;
    }

    // final aggregation (f32) + e2n (wide 3-term GEMM, f32 row-major out)
    segsum8<<<cdiv(NN, 4), 256, 0, stream>>>(stateb + o * HID, counts, bucket, nullptr, sfin);
    build_Ae2n_split8<<<cdiv((long)NN * 84, 256), 256, 0, stream>>>(d_in[0], sfin, Aqh, Aql, flags);
    gemm3w<<<cdiv(NN, 128), 1024, 0, stream>>>(Aqh, Aql, WTqh, WTql, d_in[9], hn, 1, NN, 672, flags);

    // pool + fused ffn (all f32)
    graph_starts<<<cdiv(NN, 256), 256, 0, stream>>>(b32, gstart, NN, G);
    pool_nodes<<<G, 256, 0, stream>>>(hn, gstart, Apool);
    ffn_fused<<<G / 8, 256, 0, stream>>>(Apool, d_in[10], d_in[11], d_in[12], d_in[13], d_out, flags);
}